// Round 1
// baseline (486.941 us; speedup 1.0000x reference)
//
#include <hip/hip_runtime.h>
#include <hip/hip_bf16.h>
#include <cstdint>
#include <cstddef>

typedef __hip_bfloat16 bf16;
typedef short short8 __attribute__((ext_vector_type(8)));
typedef float f32x4 __attribute__((ext_vector_type(4)));

#define S_LEN 2048
#define DMODEL 2048
#define NQKV 6144
#define NHEADS 32
#define HDIM 64

__device__ __forceinline__ void async_copy16(const bf16* g, bf16* l) {
  __builtin_amdgcn_global_load_lds(
      (const __attribute__((address_space(1))) void*)g,
      (__attribute__((address_space(3))) void*)l, 16, 0, 0);
}

__device__ __forceinline__ f32x4 mfma_bf16(short8 a, short8 b, f32x4 c) {
  return __builtin_amdgcn_mfma_f32_16x16x32_bf16(a, b, c, 0, 0, 0);
}

// ---------------- fp32 -> bf16 convert ----------------
__global__ __launch_bounds__(256) void cvt_kernel(const float* __restrict__ src,
                                                  bf16* __restrict__ dst, int n4) {
  const int i = blockIdx.x * 256 + threadIdx.x;
  if (i >= n4) return;
  const float4 v = ((const float4*)src)[i];
  union { bf16 h[4]; ushort4 u; } tmp;
  tmp.h[0] = __float2bfloat16(v.x);
  tmp.h[1] = __float2bfloat16(v.y);
  tmp.h[2] = __float2bfloat16(v.z);
  tmp.h[3] = __float2bfloat16(v.w);
  ((ushort4*)dst)[i] = tmp.u;
}

// ---------------- GEMM1: qkv = x @ Wqkv^T, fused RoPE epilogue ----------------
// A: [2048][2048] bf16 row-major; W: [6144][2048] bf16 row-major (B^T layout).
// grid (N/128, M/128), block 256 (4 waves, 2x2 wave grid, each wave 64x64).
__global__ __launch_bounds__(256) void gemm_qkv(const bf16* __restrict__ A,
                                                const bf16* __restrict__ W,
                                                bf16* __restrict__ q_ws,
                                                bf16* __restrict__ k_ws,
                                                bf16* __restrict__ v_ws) {
  constexpr int K = DMODEL;
  __shared__ bf16 As[128 * 32];
  __shared__ bf16 Ws[128 * 32];
  const int tid = threadIdx.x;
  const int wave = tid >> 6, lane = tid & 63;
  const int wm = wave >> 1, wn = wave & 1;
  const int m0 = blockIdx.y * 128, n0 = blockIdx.x * 128;
  const int sr = wave * 16 + (lane >> 2);   // staging row within 64-row issue
  const int sc = (lane & 3) * 8;            // staging col (8 bf16 = 16B)
  const int fr = lane & 15, fq = lane >> 4;

  const f32x4 zero = {0.f, 0.f, 0.f, 0.f};
  f32x4 acc[4][4];
  for (int i = 0; i < 4; ++i)
    for (int j = 0; j < 4; ++j) acc[i][j] = zero;

  for (int kt = 0; kt < K; kt += 32) {
    __syncthreads();
    for (int i2 = 0; i2 < 2; ++i2) {
      async_copy16(A + (size_t)(m0 + i2 * 64 + sr) * K + kt + sc,
                   &As[(i2 * 64 + wave * 16) * 32]);
      async_copy16(W + (size_t)(n0 + i2 * 64 + sr) * K + kt + sc,
                   &Ws[(i2 * 64 + wave * 16) * 32]);
    }
    __syncthreads();
    short8 a[4], b[4];
    for (int i = 0; i < 4; ++i)
      a[i] = *(const short8*)&As[(wm * 64 + i * 16 + fr) * 32 + fq * 8];
    for (int j = 0; j < 4; ++j)
      b[j] = *(const short8*)&Ws[(wn * 64 + j * 16 + fr) * 32 + fq * 8];
    for (int i = 0; i < 4; ++i)
      for (int j = 0; j < 4; ++j)
        acc[i][j] = mfma_bf16(a[i], b[j], acc[i][j]);
  }

  // epilogue: wave's 64-col slab = exactly one head of one section
  const int colb = n0 + wn * 64;
  const int sect = colb >> 11;          // 0=q, 1=k, 2=v
  const int h = (colb & 2047) >> 6;
  const int col = fr, rq = fq * 4;

  if (sect < 2) {
    bf16* dst = ((sect == 0) ? q_ws : k_ws) + (size_t)h * S_LEN * HDIM;
    for (int jl = 0; jl < 2; ++jl) {
      const int dh = jl * 16 + col;     // 0..31 -> pairs with dh+32 (tile jl+2)
      const float freq = powf(10000.0f, -(float)dh * (1.0f / 32.0f));
      for (int i = 0; i < 4; ++i) {
        const int base_row = m0 + wm * 64 + i * 16 + rq;
        for (int r = 0; r < 4; ++r) {
          const int srow = base_row + r;
          float sn, cs;
          sincosf((float)srow * freq, &sn, &cs);
          const float xl = acc[i][jl][r], xh = acc[i][jl + 2][r];
          dst[(size_t)srow * HDIM + dh]      = __float2bfloat16(xl * cs - xh * sn);
          dst[(size_t)srow * HDIM + dh + 32] = __float2bfloat16(xh * cs + xl * sn);
        }
      }
    }
  } else {
    bf16* dst = v_ws + (size_t)h * S_LEN * HDIM;
    for (int j = 0; j < 4; ++j) {
      const int dh = j * 16 + col;
      for (int i = 0; i < 4; ++i) {
        const int base_row = m0 + wm * 64 + i * 16 + rq;
        for (int r = 0; r < 4; ++r)
          dst[(size_t)(base_row + r) * HDIM + dh] = __float2bfloat16(acc[i][j][r]);
      }
    }
  }
}

// ---------------- V transpose: [h][s][dh] -> [h][dh][s] ----------------
__global__ __launch_bounds__(256) void transpose_v(const bf16* __restrict__ v,
                                                   bf16* __restrict__ vt) {
  __shared__ bf16 t[64 * 66];
  const int h = blockIdx.y, s0 = blockIdx.x * 64;
  const int tid = threadIdx.x;
  const bf16* src = v + (size_t)h * S_LEN * HDIM;
  bf16* dst = vt + (size_t)h * HDIM * S_LEN;
  for (int rep = 0; rep < 16; ++rep) {
    const int idx = rep * 256 + tid;
    const int sl = idx >> 6, dh = idx & 63;
    t[sl * 66 + dh] = src[(size_t)(s0 + sl) * HDIM + dh];
  }
  __syncthreads();
  for (int rep = 0; rep < 16; ++rep) {
    const int idx = rep * 256 + tid;
    const int dh = idx >> 6, sl = idx & 63;
    dst[(size_t)dh * S_LEN + s0 + sl] = t[sl * 66 + dh];
  }
}

// ---------------- flash attention (causal) ----------------
// grid (S/64, H), block 256. Wave w owns Q rows qt*64 + w*16 .. +16.
__global__ __launch_bounds__(256) void attn_kernel(const bf16* __restrict__ q_ws,
                                                   const bf16* __restrict__ k_ws,
                                                   const bf16* __restrict__ vt_ws,
                                                   bf16* __restrict__ attn_out) {
  const int qt = blockIdx.x;
  const int h = blockIdx.y;
  const int tid = threadIdx.x, wave = tid >> 6, lane = tid & 63;
  const int col = lane & 15, fq = lane >> 4, rq = fq * 4;
  const int row0 = qt * 64 + wave * 16;

  __shared__ bf16 p_lds[4][16 * 72];  // stride 72 elem = 144B (16B aligned, conflict-lite)
  bf16* pl = p_lds[wave];

  const bf16* qh = q_ws + (size_t)h * S_LEN * HDIM;
  const bf16* kh = k_ws + (size_t)h * S_LEN * HDIM;
  const bf16* vh = vt_ws + (size_t)h * HDIM * S_LEN;

  short8 qf[2];
  for (int ks = 0; ks < 2; ++ks)
    qf[ks] = *(const short8*)&qh[(size_t)(row0 + col) * HDIM + ks * 32 + fq * 8];

  const f32x4 zero = {0.f, 0.f, 0.f, 0.f};
  f32x4 o_acc[4] = {zero, zero, zero, zero};
  float m_i[4], l_i[4];
  for (int r = 0; r < 4; ++r) { m_i[r] = -1e30f; l_i[r] = 0.f; }

  for (int kt = 0; kt <= qt; ++kt) {
    const int k0 = kt * 64;
    f32x4 s_acc[4] = {zero, zero, zero, zero};
    for (int n = 0; n < 4; ++n)
      for (int ks = 0; ks < 2; ++ks) {
        short8 kf = *(const short8*)&kh[(size_t)(k0 + n * 16 + col) * HDIM + ks * 32 + fq * 8];
        s_acc[n] = mfma_bf16(qf[ks], kf, s_acc[n]);
      }
    const bool bound = (kt == qt);
    float alpha[4];
    for (int r = 0; r < 4; ++r) {
      const int grow = row0 + rq + r;
      float vmax = -1e30f;
      for (int n = 0; n < 4; ++n) {
        float s = s_acc[n][r] * 0.125f;
        if (bound && (k0 + n * 16 + col) > grow) s = -1e30f;
        s_acc[n][r] = s;
        vmax = fmaxf(vmax, s);
      }
      for (int mm = 1; mm < 16; mm <<= 1) vmax = fmaxf(vmax, __shfl_xor(vmax, mm, 64));
      const float mnew = fmaxf(m_i[r], vmax);
      alpha[r] = __expf(m_i[r] - mnew);
      m_i[r] = mnew;
      float rs = 0.f;
      for (int n = 0; n < 4; ++n) {
        const float p = __expf(s_acc[n][r] - mnew);
        s_acc[n][r] = p;
        rs += p;
      }
      for (int mm = 1; mm < 16; mm <<= 1) rs += __shfl_xor(rs, mm, 64);
      l_i[r] = l_i[r] * alpha[r] + rs;
    }
    for (int n = 0; n < 4; ++n)
      for (int r = 0; r < 4; ++r) o_acc[n][r] *= alpha[r];
    // P: C-layout -> LDS -> A-layout (bf16)
    for (int n = 0; n < 4; ++n)
      for (int r = 0; r < 4; ++r)
        pl[(rq + r) * 72 + n * 16 + col] = __float2bfloat16(s_acc[n][r]);
    short8 pa[2];
    for (int ks = 0; ks < 2; ++ks)
      pa[ks] = *(const short8*)&pl[col * 72 + ks * 32 + fq * 8];
    for (int n = 0; n < 4; ++n)
      for (int ks = 0; ks < 2; ++ks) {
        short8 vf = *(const short8*)&vh[(size_t)(n * 16 + col) * S_LEN + k0 + ks * 32 + fq * 8];
        o_acc[n] = mfma_bf16(pa[ks], vf, o_acc[n]);
      }
  }

  for (int r = 0; r < 4; ++r) {
    const float inv = 1.0f / l_i[r];
    for (int n = 0; n < 4; ++n) o_acc[n][r] *= inv;
  }
  for (int n = 0; n < 4; ++n)
    for (int r = 0; r < 4; ++r)
      attn_out[(size_t)(row0 + rq + r) * DMODEL + h * HDIM + n * 16 + col] =
          __float2bfloat16(o_acc[n][r]);
}

// ---------------- GEMM2: out = attn @ Wo^T, fused residual+gate ----------------
__global__ __launch_bounds__(256) void gemm_out(const bf16* __restrict__ A,
                                                const bf16* __restrict__ W,
                                                const float* __restrict__ xres,
                                                const float* __restrict__ gate,
                                                float* __restrict__ out) {
  constexpr int K = DMODEL;
  __shared__ bf16 As[128 * 32];
  __shared__ bf16 Ws[128 * 32];
  const int tid = threadIdx.x;
  const int wave = tid >> 6, lane = tid & 63;
  const int wm = wave >> 1, wn = wave & 1;
  const int m0 = blockIdx.y * 128, n0 = blockIdx.x * 128;
  const int sr = wave * 16 + (lane >> 2);
  const int sc = (lane & 3) * 8;
  const int fr = lane & 15, fq = lane >> 4;

  const f32x4 zero = {0.f, 0.f, 0.f, 0.f};
  f32x4 acc[4][4];
  for (int i = 0; i < 4; ++i)
    for (int j = 0; j < 4; ++j) acc[i][j] = zero;

  for (int kt = 0; kt < K; kt += 32) {
    __syncthreads();
    for (int i2 = 0; i2 < 2; ++i2) {
      async_copy16(A + (size_t)(m0 + i2 * 64 + sr) * K + kt + sc,
                   &As[(i2 * 64 + wave * 16) * 32]);
      async_copy16(W + (size_t)(n0 + i2 * 64 + sr) * K + kt + sc,
                   &Ws[(i2 * 64 + wave * 16) * 32]);
    }
    __syncthreads();
    short8 a[4], b[4];
    for (int i = 0; i < 4; ++i)
      a[i] = *(const short8*)&As[(wm * 64 + i * 16 + fr) * 32 + fq * 8];
    for (int j = 0; j < 4; ++j)
      b[j] = *(const short8*)&Ws[(wn * 64 + j * 16 + fr) * 32 + fq * 8];
    for (int i = 0; i < 4; ++i)
      for (int j = 0; j < 4; ++j)
        acc[i][j] = mfma_bf16(a[i], b[j], acc[i][j]);
  }

  const int col = fr, rq = fq * 4;
  for (int j = 0; j < 4; ++j) {
    const int cc = n0 + wn * 64 + j * 16 + col;
    const float g = gate[cc];
    for (int i = 0; i < 4; ++i) {
      const int base_row = m0 + wm * 64 + i * 16 + rq;
      for (int r = 0; r < 4; ++r) {
        const size_t idx = (size_t)(base_row + r) * DMODEL + cc;
        out[idx] = xres[idx] + g * acc[i][j][r];
      }
    }
  }
}

extern "C" void kernel_launch(void* const* d_in, const int* in_sizes, int n_in,
                              void* d_out, int out_size, void* d_ws, size_t ws_size,
                              hipStream_t stream) {
  const float* x    = (const float*)d_in[0];
  const float* Wqkv = (const float*)d_in[1];
  const float* Wo   = (const float*)d_in[2];
  const float* gate = (const float*)d_in[3];
  float* out = (float*)d_out;

  char* ws = (char*)d_ws;
  const size_t MB = 1024 * 1024;
  bf16* xb      = (bf16*)(ws);                 // 8 MB   (dead after gemm_qkv)
  bf16* wqkvb   = (bf16*)(ws + 8 * MB);        // 24 MB  (dead after gemm_qkv)
  bf16* wob     = (bf16*)(ws + 32 * MB);       // 8 MB
  bf16* q_ws    = (bf16*)(ws + 40 * MB);       // 8 MB
  bf16* k_ws    = (bf16*)(ws + 48 * MB);       // 8 MB
  bf16* v_ws    = (bf16*)(ws + 56 * MB);       // 8 MB
  bf16* vt_ws   = (bf16*)(ws + 8 * MB);        // aliases wqkvb
  bf16* attn_ws = (bf16*)(ws);                 // aliases xb

  cvt_kernel<<<dim3(4096), 256, 0, stream>>>(x, xb, 1048576);
  cvt_kernel<<<dim3(12288), 256, 0, stream>>>(Wqkv, wqkvb, 3145728);
  cvt_kernel<<<dim3(4096), 256, 0, stream>>>(Wo, wob, 1048576);

  gemm_qkv<<<dim3(NQKV / 128, DMODEL / 128), 256, 0, stream>>>(xb, wqkvb, q_ws, k_ws, v_ws);
  transpose_v<<<dim3(S_LEN / 64, NHEADS), 256, 0, stream>>>(v_ws, vt_ws);
  attn_kernel<<<dim3(S_LEN / 64, NHEADS), 256, 0, stream>>>(q_ws, k_ws, vt_ws, attn_ws);
  gemm_out<<<dim3(DMODEL / 128, DMODEL / 128), 256, 0, stream>>>(attn_ws, wob, x, gate, out);
}

// Round 2
// 393.679 us; speedup vs baseline: 1.2369x; 1.2369x over previous
//
#include <hip/hip_runtime.h>
#include <hip/hip_bf16.h>
#include <cstdint>
#include <cstddef>

typedef __hip_bfloat16 bf16;
typedef short short8 __attribute__((ext_vector_type(8)));
typedef float f32x4 __attribute__((ext_vector_type(4)));

#define S_LEN 2048
#define DMODEL 2048
#define NQKV 6144
#define NHEADS 32
#define HDIM 64
// 0.125 (1/sqrt(64)) * log2(e): softmax done in exp2 domain on RAW scores
#define SOFTMAX_SCL 0.1803368801111204f

__device__ __forceinline__ void async_copy16(const bf16* g, bf16* l) {
  __builtin_amdgcn_global_load_lds(
      (const __attribute__((address_space(1))) void*)g,
      (__attribute__((address_space(3))) void*)l, 16, 0, 0);
}

__device__ __forceinline__ f32x4 mfma_bf16(short8 a, short8 b, f32x4 c) {
  return __builtin_amdgcn_mfma_f32_16x16x32_bf16(a, b, c, 0, 0, 0);
}

// ---------------- fused fp32 -> bf16 convert of x, Wqkv, Wo ----------------
// ranges (in float4 units): x 1048576, Wqkv 3145728, Wo 1048576 -> 5242880 total
__global__ __launch_bounds__(256) void cvt3_kernel(const float* __restrict__ sx,
                                                   bf16* __restrict__ dx,
                                                   const float* __restrict__ sw,
                                                   bf16* __restrict__ dw,
                                                   const float* __restrict__ so,
                                                   bf16* __restrict__ dov) {
  int i = blockIdx.x * 256 + threadIdx.x;
  const float* s;
  bf16* d;
  if (i < 1048576) {
    s = sx; d = dx;
  } else if (i < 4194304) {
    s = sw; d = dw; i -= 1048576;
  } else {
    s = so; d = dov; i -= 4194304;
  }
  const float4 v = ((const float4*)s)[i];
  union { bf16 h[4]; ushort4 u; } tmp;
  tmp.h[0] = __float2bfloat16(v.x);
  tmp.h[1] = __float2bfloat16(v.y);
  tmp.h[2] = __float2bfloat16(v.z);
  tmp.h[3] = __float2bfloat16(v.w);
  ((ushort4*)d)[i] = tmp.u;
}

// ---------------- GEMM1: qkv = x @ Wqkv^T, fused RoPE epilogue ----------------
__global__ __launch_bounds__(256) void gemm_qkv(const bf16* __restrict__ A,
                                                const bf16* __restrict__ W,
                                                bf16* __restrict__ q_ws,
                                                bf16* __restrict__ k_ws,
                                                bf16* __restrict__ v_ws) {
  constexpr int K = DMODEL;
  __shared__ bf16 As[128 * 32];
  __shared__ bf16 Ws[128 * 32];
  const int tid = threadIdx.x;
  const int wave = tid >> 6, lane = tid & 63;
  const int wm = wave >> 1, wn = wave & 1;
  const int m0 = blockIdx.y * 128, n0 = blockIdx.x * 128;
  const int sr = wave * 16 + (lane >> 2);
  const int sc = (lane & 3) * 8;
  const int fr = lane & 15, fq = lane >> 4;

  const f32x4 zero = {0.f, 0.f, 0.f, 0.f};
  f32x4 acc[4][4];
  for (int i = 0; i < 4; ++i)
    for (int j = 0; j < 4; ++j) acc[i][j] = zero;

  for (int kt = 0; kt < K; kt += 32) {
    __syncthreads();
    for (int i2 = 0; i2 < 2; ++i2) {
      async_copy16(A + (size_t)(m0 + i2 * 64 + sr) * K + kt + sc,
                   &As[(i2 * 64 + wave * 16) * 32]);
      async_copy16(W + (size_t)(n0 + i2 * 64 + sr) * K + kt + sc,
                   &Ws[(i2 * 64 + wave * 16) * 32]);
    }
    __syncthreads();
    short8 a[4], b[4];
    for (int i = 0; i < 4; ++i)
      a[i] = *(const short8*)&As[(wm * 64 + i * 16 + fr) * 32 + fq * 8];
    for (int j = 0; j < 4; ++j)
      b[j] = *(const short8*)&Ws[(wn * 64 + j * 16 + fr) * 32 + fq * 8];
    for (int i = 0; i < 4; ++i)
      for (int j = 0; j < 4; ++j)
        acc[i][j] = mfma_bf16(a[i], b[j], acc[i][j]);
  }

  const int colb = n0 + wn * 64;
  const int sect = colb >> 11;          // 0=q, 1=k, 2=v
  const int h = (colb & 2047) >> 6;
  const int col = fr, rq = fq * 4;

  if (sect < 2) {
    bf16* dst = ((sect == 0) ? q_ws : k_ws) + (size_t)h * S_LEN * HDIM;
    for (int jl = 0; jl < 2; ++jl) {
      const int dh = jl * 16 + col;     // pairs with dh+32 in acc tile jl+2
      const float freq = powf(10000.0f, -(float)dh * (1.0f / 32.0f));
      for (int i = 0; i < 4; ++i) {
        const int base_row = m0 + wm * 64 + i * 16 + rq;
        for (int r = 0; r < 4; ++r) {
          const int srow = base_row + r;
          float sn, cs;
          sincosf((float)srow * freq, &sn, &cs);
          const float xl = acc[i][jl][r], xh = acc[i][jl + 2][r];
          dst[(size_t)srow * HDIM + dh]      = __float2bfloat16(xl * cs - xh * sn);
          dst[(size_t)srow * HDIM + dh + 32] = __float2bfloat16(xh * cs + xl * sn);
        }
      }
    }
  } else {
    bf16* dst = v_ws + (size_t)h * S_LEN * HDIM;
    for (int j = 0; j < 4; ++j) {
      const int dh = j * 16 + col;
      for (int i = 0; i < 4; ++i) {
        const int base_row = m0 + wm * 64 + i * 16 + rq;
        for (int r = 0; r < 4; ++r)
          dst[(size_t)(base_row + r) * HDIM + dh] = __float2bfloat16(acc[i][j][r]);
      }
    }
  }
}

// ---------------- V transpose: [h][s][dh] -> [h][dh][s] ----------------
__global__ __launch_bounds__(256) void transpose_v(const bf16* __restrict__ v,
                                                   bf16* __restrict__ vt) {
  __shared__ bf16 t[64 * 66];
  const int h = blockIdx.y, s0 = blockIdx.x * 64;
  const int tid = threadIdx.x;
  const bf16* src = v + (size_t)h * S_LEN * HDIM;
  bf16* dst = vt + (size_t)h * HDIM * S_LEN;
  for (int rep = 0; rep < 16; ++rep) {
    const int idx = rep * 256 + tid;
    const int sl = idx >> 6, dh = idx & 63;
    t[sl * 66 + dh] = src[(size_t)(s0 + sl) * HDIM + dh];
  }
  __syncthreads();
  for (int rep = 0; rep < 16; ++rep) {
    const int idx = rep * 256 + tid;
    const int dh = idx >> 6, sl = idx & 63;
    dst[(size_t)dh * S_LEN + s0 + sl] = t[sl * 66 + dh];
  }
}

// ---------------- flash attention (causal), latency-pipelined ----------------
// grid 1024 blocks (LPT order: heavy q-tiles first), 4 waves; wave w owns
// q rows qt*64 + w*16. K-frags double-buffered across the k-loop back-edge;
// V loads issued before softmax so the VALU chain hides both load batches.
__global__ __launch_bounds__(256) void attn_kernel(const bf16* __restrict__ q_ws,
                                                   const bf16* __restrict__ k_ws,
                                                   const bf16* __restrict__ vt_ws,
                                                   bf16* __restrict__ attn_out) {
  const int bid = blockIdx.x;
  const int pid = bid >> 5;
  const int h = bid & 31;
  // LPT: pid even -> qt = 31 - pid/2 (heavy first); pid odd -> qt = pid/2
  const int qt = (pid & 1) ? (pid >> 1) : (31 - (pid >> 1));

  const int tid = threadIdx.x, wave = tid >> 6, lane = tid & 63;
  const int col = lane & 15, fq = lane >> 4, rq = fq * 4;
  const int row0 = qt * 64 + wave * 16;

  __shared__ bf16 p_lds[4][16 * 72];
  bf16* pl = p_lds[wave];

  const bf16* qh = q_ws + (size_t)h * S_LEN * HDIM;
  const bf16* kh = k_ws + (size_t)h * S_LEN * HDIM;
  const bf16* vh = vt_ws + (size_t)h * HDIM * S_LEN;

  short8 qf[2];
#pragma unroll
  for (int ks = 0; ks < 2; ++ks)
    qf[ks] = *(const short8*)&qh[(size_t)(row0 + col) * HDIM + ks * 32 + fq * 8];

  const f32x4 zero = {0.f, 0.f, 0.f, 0.f};
  f32x4 o_acc[4] = {zero, zero, zero, zero};
  float m_i[4], l_i[4];
#pragma unroll
  for (int r = 0; r < 4; ++r) { m_i[r] = -1e30f; l_i[r] = 0.f; }

  short8 kfa[8], kfb[8];

  auto loadK = [&](int kt, short8* kf) {
    const int k0 = kt * 64;
#pragma unroll
    for (int n = 0; n < 4; ++n)
#pragma unroll
      for (int ks = 0; ks < 2; ++ks)
        kf[n * 2 + ks] =
            *(const short8*)&kh[(size_t)(k0 + n * 16 + col) * HDIM + ks * 32 + fq * 8];
  };

  auto body = [&](int kt, short8* cur, short8* nxt) {
    const int k0 = kt * 64;
    f32x4 s_acc[4] = {zero, zero, zero, zero};
#pragma unroll
    for (int n = 0; n < 4; ++n)
#pragma unroll
      for (int ks = 0; ks < 2; ++ks)
        s_acc[n] = mfma_bf16(qf[ks], cur[n * 2 + ks], s_acc[n]);

    // issue V loads now; consumed after softmax (latency hidden under VALU)
    short8 vf[8];
#pragma unroll
    for (int n = 0; n < 4; ++n)
#pragma unroll
      for (int ks = 0; ks < 2; ++ks)
        vf[n * 2 + ks] =
            *(const short8*)&vh[(size_t)(n * 16 + col) * S_LEN + k0 + ks * 32 + fq * 8];

    // prefetch next K-tile fragments; consumed at next iteration's QK
    if (kt < qt) loadK(kt + 1, nxt);

    const bool bound = (kt == qt);
    float alpha[4];
#pragma unroll
    for (int r = 0; r < 4; ++r) {
      const int grow = row0 + rq + r;
      float vmax = -1e30f;
#pragma unroll
      for (int n = 0; n < 4; ++n) {
        float s = s_acc[n][r];  // RAW score; scale folded into exp2
        if (bound && (k0 + n * 16 + col) > grow) s = -1e30f;
        s_acc[n][r] = s;
        vmax = fmaxf(vmax, s);
      }
#pragma unroll
      for (int mm = 1; mm < 16; mm <<= 1) vmax = fmaxf(vmax, __shfl_xor(vmax, mm, 64));
      const float mnew = fmaxf(m_i[r], vmax);
      alpha[r] = __expf((m_i[r] - mnew) * (SOFTMAX_SCL * 0.6931471805599453f));
      m_i[r] = mnew;
      float rs = 0.f;
#pragma unroll
      for (int n = 0; n < 4; ++n) {
        const float p = __expf((s_acc[n][r] - mnew) * (SOFTMAX_SCL * 0.6931471805599453f));
        s_acc[n][r] = p;
        rs += p;
      }
#pragma unroll
      for (int mm = 1; mm < 16; mm <<= 1) rs += __shfl_xor(rs, mm, 64);
      l_i[r] = l_i[r] * alpha[r] + rs;
    }
#pragma unroll
    for (int n = 0; n < 4; ++n)
#pragma unroll
      for (int r = 0; r < 4; ++r) o_acc[n][r] *= alpha[r];

    // P: C-layout -> LDS -> A-layout (bf16)
#pragma unroll
    for (int n = 0; n < 4; ++n)
#pragma unroll
      for (int r = 0; r < 4; ++r)
        pl[(rq + r) * 72 + n * 16 + col] = __float2bfloat16(s_acc[n][r]);
    short8 pa[2];
#pragma unroll
    for (int ks = 0; ks < 2; ++ks)
      pa[ks] = *(const short8*)&pl[col * 72 + ks * 32 + fq * 8];
#pragma unroll
    for (int n = 0; n < 4; ++n)
#pragma unroll
      for (int ks = 0; ks < 2; ++ks)
        o_acc[n] = mfma_bf16(pa[ks], vf[n * 2 + ks], o_acc[n]);
  };

  loadK(0, kfa);
  int kt = 0;
  for (;;) {
    body(kt, kfa, kfb);
    if (kt >= qt) break;
    ++kt;
    body(kt, kfb, kfa);
    if (kt >= qt) break;
    ++kt;
  }

#pragma unroll
  for (int r = 0; r < 4; ++r) {
    const float inv = 1.0f / l_i[r];
#pragma unroll
    for (int n = 0; n < 4; ++n) o_acc[n][r] *= inv;
  }
#pragma unroll
  for (int n = 0; n < 4; ++n)
#pragma unroll
    for (int r = 0; r < 4; ++r)
      attn_out[(size_t)(row0 + rq + r) * DMODEL + h * HDIM + n * 16 + col] =
          __float2bfloat16(o_acc[n][r]);
}

// ---------------- GEMM2: out = attn @ Wo^T, fused residual+gate ----------------
__global__ __launch_bounds__(256) void gemm_out(const bf16* __restrict__ A,
                                                const bf16* __restrict__ W,
                                                const float* __restrict__ xres,
                                                const float* __restrict__ gate,
                                                float* __restrict__ out) {
  constexpr int K = DMODEL;
  __shared__ bf16 As[128 * 32];
  __shared__ bf16 Ws[128 * 32];
  const int tid = threadIdx.x;
  const int wave = tid >> 6, lane = tid & 63;
  const int wm = wave >> 1, wn = wave & 1;
  const int m0 = blockIdx.y * 128, n0 = blockIdx.x * 128;
  const int sr = wave * 16 + (lane >> 2);
  const int sc = (lane & 3) * 8;
  const int fr = lane & 15, fq = lane >> 4;

  const f32x4 zero = {0.f, 0.f, 0.f, 0.f};
  f32x4 acc[4][4];
  for (int i = 0; i < 4; ++i)
    for (int j = 0; j < 4; ++j) acc[i][j] = zero;

  for (int kt = 0; kt < K; kt += 32) {
    __syncthreads();
    for (int i2 = 0; i2 < 2; ++i2) {
      async_copy16(A + (size_t)(m0 + i2 * 64 + sr) * K + kt + sc,
                   &As[(i2 * 64 + wave * 16) * 32]);
      async_copy16(W + (size_t)(n0 + i2 * 64 + sr) * K + kt + sc,
                   &Ws[(i2 * 64 + wave * 16) * 32]);
    }
    __syncthreads();
    short8 a[4], b[4];
    for (int i = 0; i < 4; ++i)
      a[i] = *(const short8*)&As[(wm * 64 + i * 16 + fr) * 32 + fq * 8];
    for (int j = 0; j < 4; ++j)
      b[j] = *(const short8*)&Ws[(wn * 64 + j * 16 + fr) * 32 + fq * 8];
    for (int i = 0; i < 4; ++i)
      for (int j = 0; j < 4; ++j)
        acc[i][j] = mfma_bf16(a[i], b[j], acc[i][j]);
  }

  const int col = fr, rq = fq * 4;
  for (int j = 0; j < 4; ++j) {
    const int cc = n0 + wn * 64 + j * 16 + col;
    const float g = gate[cc];
    for (int i = 0; i < 4; ++i) {
      const int base_row = m0 + wm * 64 + i * 16 + rq;
      for (int r = 0; r < 4; ++r) {
        const size_t idx = (size_t)(base_row + r) * DMODEL + cc;
        out[idx] = xres[idx] + g * acc[i][j][r];
      }
    }
  }
}

extern "C" void kernel_launch(void* const* d_in, const int* in_sizes, int n_in,
                              void* d_out, int out_size, void* d_ws, size_t ws_size,
                              hipStream_t stream) {
  const float* x    = (const float*)d_in[0];
  const float* Wqkv = (const float*)d_in[1];
  const float* Wo   = (const float*)d_in[2];
  const float* gate = (const float*)d_in[3];
  float* out = (float*)d_out;

  char* ws = (char*)d_ws;
  const size_t MB = 1024 * 1024;
  bf16* xb      = (bf16*)(ws);                 // 8 MB   (dead after gemm_qkv)
  bf16* wqkvb   = (bf16*)(ws + 8 * MB);        // 24 MB  (dead after gemm_qkv)
  bf16* wob     = (bf16*)(ws + 32 * MB);       // 8 MB
  bf16* q_ws    = (bf16*)(ws + 40 * MB);       // 8 MB
  bf16* k_ws    = (bf16*)(ws + 48 * MB);       // 8 MB
  bf16* v_ws    = (bf16*)(ws + 56 * MB);       // 8 MB
  bf16* vt_ws   = (bf16*)(ws + 8 * MB);        // aliases wqkvb
  bf16* attn_ws = (bf16*)(ws);                 // aliases xb

  cvt3_kernel<<<dim3(20480), 256, 0, stream>>>(x, xb, Wqkv, wqkvb, Wo, wob);

  gemm_qkv<<<dim3(NQKV / 128, DMODEL / 128), 256, 0, stream>>>(xb, wqkvb, q_ws, k_ws, v_ws);
  transpose_v<<<dim3(S_LEN / 64, NHEADS), 256, 0, stream>>>(v_ws, vt_ws);
  attn_kernel<<<dim3(1024), 256, 0, stream>>>(q_ws, k_ws, vt_ws, attn_ws);
  gemm_out<<<dim3(DMODEL / 128, DMODEL / 128), 256, 0, stream>>>(attn_ws, wob, x, gate, out);
}

// Round 3
// 377.487 us; speedup vs baseline: 1.2900x; 1.0429x over previous
//
#include <hip/hip_runtime.h>
#include <hip/hip_bf16.h>
#include <cstdint>
#include <cstddef>

typedef __hip_bfloat16 bf16;
typedef short short8 __attribute__((ext_vector_type(8)));
typedef float f32x4 __attribute__((ext_vector_type(4)));

#define S_LEN 2048
#define DMODEL 2048
#define NQKV 6144
#define NHEADS 32
#define HDIM 64

__device__ __forceinline__ void async_copy16(const bf16* g, bf16* l) {
  __builtin_amdgcn_global_load_lds(
      (const __attribute__((address_space(1))) void*)g,
      (__attribute__((address_space(3))) void*)l, 16, 0, 0);
}

__device__ __forceinline__ f32x4 mfma_bf16(short8 a, short8 b, f32x4 c) {
  return __builtin_amdgcn_mfma_f32_16x16x32_bf16(a, b, c, 0, 0, 0);
}

// ---------------- fused fp32 -> bf16 convert of x, Wqkv, Wo ----------------
__global__ __launch_bounds__(256) void cvt3_kernel(const float* __restrict__ sx,
                                                   bf16* __restrict__ dx,
                                                   const float* __restrict__ sw,
                                                   bf16* __restrict__ dw,
                                                   const float* __restrict__ so,
                                                   bf16* __restrict__ dov) {
  int i = blockIdx.x * 256 + threadIdx.x;
  const float* s;
  bf16* d;
  if (i < 1048576) {
    s = sx; d = dx;
  } else if (i < 4194304) {
    s = sw; d = dw; i -= 1048576;
  } else {
    s = so; d = dov; i -= 4194304;
  }
  const float4 v = ((const float4*)s)[i];
  union { bf16 h[4]; ushort4 u; } tmp;
  tmp.h[0] = __float2bfloat16(v.x);
  tmp.h[1] = __float2bfloat16(v.y);
  tmp.h[2] = __float2bfloat16(v.z);
  tmp.h[3] = __float2bfloat16(v.w);
  ((ushort4*)d)[i] = tmp.u;
}

// ---------------- GEMM1: qkv = x @ Wqkv^T, fused RoPE epilogue ----------------
__global__ __launch_bounds__(256) void gemm_qkv(const bf16* __restrict__ A,
                                                const bf16* __restrict__ W,
                                                bf16* __restrict__ q_ws,
                                                bf16* __restrict__ k_ws,
                                                bf16* __restrict__ v_ws) {
  constexpr int K = DMODEL;
  __shared__ bf16 As[128 * 32];
  __shared__ bf16 Ws[128 * 32];
  const int tid = threadIdx.x;
  const int wave = tid >> 6, lane = tid & 63;
  const int wm = wave >> 1, wn = wave & 1;
  const int m0 = blockIdx.y * 128, n0 = blockIdx.x * 128;
  const int sr = wave * 16 + (lane >> 2);
  const int sc = (lane & 3) * 8;
  const int fr = lane & 15, fq = lane >> 4;

  const f32x4 zero = {0.f, 0.f, 0.f, 0.f};
  f32x4 acc[4][4];
  for (int i = 0; i < 4; ++i)
    for (int j = 0; j < 4; ++j) acc[i][j] = zero;

  for (int kt = 0; kt < K; kt += 32) {
    __syncthreads();
    for (int i2 = 0; i2 < 2; ++i2) {
      async_copy16(A + (size_t)(m0 + i2 * 64 + sr) * K + kt + sc,
                   &As[(i2 * 64 + wave * 16) * 32]);
      async_copy16(W + (size_t)(n0 + i2 * 64 + sr) * K + kt + sc,
                   &Ws[(i2 * 64 + wave * 16) * 32]);
    }
    __syncthreads();
    short8 a[4], b[4];
    for (int i = 0; i < 4; ++i)
      a[i] = *(const short8*)&As[(wm * 64 + i * 16 + fr) * 32 + fq * 8];
    for (int j = 0; j < 4; ++j)
      b[j] = *(const short8*)&Ws[(wn * 64 + j * 16 + fr) * 32 + fq * 8];
    for (int i = 0; i < 4; ++i)
      for (int j = 0; j < 4; ++j)
        acc[i][j] = mfma_bf16(a[i], b[j], acc[i][j]);
  }

  const int colb = n0 + wn * 64;
  const int sect = colb >> 11;          // 0=q, 1=k, 2=v
  const int h = (colb & 2047) >> 6;
  const int col = fr, rq = fq * 4;

  if (sect < 2) {
    bf16* dst = ((sect == 0) ? q_ws : k_ws) + (size_t)h * S_LEN * HDIM;
    for (int jl = 0; jl < 2; ++jl) {
      const int dh = jl * 16 + col;     // pairs with dh+32 in acc tile jl+2
      const float freq = powf(10000.0f, -(float)dh * (1.0f / 32.0f));
      for (int i = 0; i < 4; ++i) {
        const int base_row = m0 + wm * 64 + i * 16 + rq;
        for (int r = 0; r < 4; ++r) {
          const int srow = base_row + r;
          float sn, cs;
          sincosf((float)srow * freq, &sn, &cs);
          const float xl = acc[i][jl][r], xh = acc[i][jl + 2][r];
          dst[(size_t)srow * HDIM + dh]      = __float2bfloat16(xl * cs - xh * sn);
          dst[(size_t)srow * HDIM + dh + 32] = __float2bfloat16(xh * cs + xl * sn);
        }
      }
    }
  } else {
    bf16* dst = v_ws + (size_t)h * S_LEN * HDIM;
    for (int j = 0; j < 4; ++j) {
      const int dh = j * 16 + col;
      for (int i = 0; i < 4; ++i) {
        const int base_row = m0 + wm * 64 + i * 16 + rq;
        for (int r = 0; r < 4; ++r)
          dst[(size_t)(base_row + r) * HDIM + dh] = __float2bfloat16(acc[i][j][r]);
      }
    }
  }
}

// ---------------- V transpose: [h][s][dh] -> [h][dh][s] ----------------
__global__ __launch_bounds__(256) void transpose_v(const bf16* __restrict__ v,
                                                   bf16* __restrict__ vt) {
  __shared__ bf16 t[64 * 66];
  const int h = blockIdx.y, s0 = blockIdx.x * 64;
  const int tid = threadIdx.x;
  const bf16* src = v + (size_t)h * S_LEN * HDIM;
  bf16* dst = vt + (size_t)h * HDIM * S_LEN;
  for (int rep = 0; rep < 16; ++rep) {
    const int idx = rep * 256 + tid;
    const int sl = idx >> 6, dh = idx & 63;
    t[sl * 66 + dh] = src[(size_t)(s0 + sl) * HDIM + dh];
  }
  __syncthreads();
  for (int rep = 0; rep < 16; ++rep) {
    const int idx = rep * 256 + tid;
    const int dh = idx >> 6, sl = idx & 63;
    dst[(size_t)dh * S_LEN + s0 + sl] = t[sl * 66 + dh];
  }
}

// ---------------- flash attention (causal), transposed-tile design ----------------
// One wave per block (64 thr), grid 4096 = 32 qt (LPT heavy-first) x 32 h x 4 sub.
// Wave owns 16 q rows. S^T = K·Q^T via operand-swapped MFMA: lane holds 16 scores
// for ONE query (col) -> softmax = in-lane reduce over 16 regs + 2 shfls.
// PV as O^T = V^T·P^T; P^T packed to LDS with 4x ds_write_b64, read back as B-frags.
__global__ __launch_bounds__(64) void attn_kernel(const bf16* __restrict__ q_ws,
                                                  const bf16* __restrict__ k_ws,
                                                  const bf16* __restrict__ vt_ws,
                                                  bf16* __restrict__ attn_out) {
  const int bid = blockIdx.x;
  const int qt = 31 - (bid >> 7);      // heavy q-tiles dispatched first (LPT)
  const int h = (bid >> 2) & 31;
  const int sub = bid & 3;

  const int lane = threadIdx.x;
  const int col = lane & 15, fq = lane >> 4;
  const int row0 = qt * 64 + sub * 16;
  const int q_glob = row0 + col;

  __shared__ bf16 pl[16 * 72];         // [q=16][key=64 + pad 8]

  const bf16* qh = q_ws + (size_t)h * S_LEN * HDIM;
  const bf16* kh = k_ws + (size_t)h * S_LEN * HDIM;
  const bf16* vh = vt_ws + (size_t)h * HDIM * S_LEN;

  short8 qf[2];  // B operand: n=q(col), k=dh
#pragma unroll
  for (int ks = 0; ks < 2; ++ks)
    qf[ks] = *(const short8*)&qh[(size_t)q_glob * HDIM + ks * 32 + fq * 8];

  const f32x4 zero = {0.f, 0.f, 0.f, 0.f};
  f32x4 o_acc[4] = {zero, zero, zero, zero};  // O^T: d-tiles, col=q, row=d
  float m_i = -1e30f, l_i = 0.f;

  short8 kfa[8], kfb[8];

  auto loadK = [&](int kt, short8* kf) {
    const int k0 = kt * 64;
#pragma unroll
    for (int n = 0; n < 4; ++n)
#pragma unroll
      for (int ks = 0; ks < 2; ++ks)
        kf[n * 2 + ks] =
            *(const short8*)&kh[(size_t)(k0 + n * 16 + col) * HDIM + ks * 32 + fq * 8];
  };

  auto body = [&](int kt, short8* cur, short8* nxt) {
    const int k0 = kt * 64;
    // S^T tile: D[m=key][n=q] — A=K frag, B=Q frag
    f32x4 s_acc[4] = {zero, zero, zero, zero};
#pragma unroll
    for (int n = 0; n < 4; ++n)
#pragma unroll
      for (int ks = 0; ks < 2; ++ks)
        s_acc[n] = mfma_bf16(cur[n * 2 + ks], qf[ks], s_acc[n]);

    // issue V loads now; consumed after softmax (latency hidden under VALU)
    short8 vf[8];
#pragma unroll
    for (int n = 0; n < 4; ++n)
#pragma unroll
      for (int ks = 0; ks < 2; ++ks)
        vf[n * 2 + ks] =
            *(const short8*)&vh[(size_t)(n * 16 + col) * S_LEN + k0 + ks * 32 + fq * 8];

    // prefetch next K-tile fragments
    if (kt < qt) loadK(kt + 1, nxt);

    // causal mask (bound tile only): key = k0 + n*16 + fq*4 + r, query = q_glob
    if (kt == qt) {
#pragma unroll
      for (int n = 0; n < 4; ++n)
#pragma unroll
        for (int r = 0; r < 4; ++r)
          if (k0 + n * 16 + fq * 4 + r > q_glob) s_acc[n][r] = -1e30f;
    }

    // in-lane max over 16 scores (one query per lane), then 2 shfl stages
    float vmax = -1e30f;
#pragma unroll
    for (int n = 0; n < 4; ++n)
#pragma unroll
      for (int r = 0; r < 4; ++r) vmax = fmaxf(vmax, s_acc[n][r]);
    vmax = fmaxf(vmax, __shfl_xor(vmax, 16, 64));
    vmax = fmaxf(vmax, __shfl_xor(vmax, 32, 64));
    const float mnew = fmaxf(m_i, vmax);
    const float alpha = __expf((m_i - mnew) * 0.125f);
    m_i = mnew;

    float rs = 0.f;
#pragma unroll
    for (int n = 0; n < 4; ++n)
#pragma unroll
      for (int r = 0; r < 4; ++r) {
        const float p = __expf((s_acc[n][r] - mnew) * 0.125f);
        s_acc[n][r] = p;
        rs += p;
      }
    rs += __shfl_xor(rs, 16, 64);
    rs += __shfl_xor(rs, 32, 64);
    l_i = l_i * alpha + rs;

#pragma unroll
    for (int n = 0; n < 4; ++n)
#pragma unroll
      for (int r = 0; r < 4; ++r) o_acc[n][r] *= alpha;

    // P^T -> LDS: lane's 4 consecutive keys for its query -> one b64 write per n
#pragma unroll
    for (int n = 0; n < 4; ++n) {
      union { bf16 hx[4]; uint2 u; } pk;
#pragma unroll
      for (int r = 0; r < 4; ++r) pk.hx[r] = __float2bfloat16(s_acc[n][r]);
      *(uint2*)&pl[col * 72 + n * 16 + fq * 4] = pk.u;
    }
    // read back as B operand: B[k=key][n=q(col)]
    short8 pa[2];
#pragma unroll
    for (int ks = 0; ks < 2; ++ks)
      pa[ks] = *(const short8*)&pl[col * 72 + ks * 32 + fq * 8];

    // O^T += V^T · P^T : A=V^T frag (m=d), B=P^T
#pragma unroll
    for (int n = 0; n < 4; ++n)
#pragma unroll
      for (int ks = 0; ks < 2; ++ks)
        o_acc[n] = mfma_bf16(vf[n * 2 + ks], pa[ks], o_acc[n]);
  };

  loadK(0, kfa);
  int kt = 0;
  for (;;) {
    body(kt, kfa, kfb);
    if (kt >= qt) break;
    ++kt;
    body(kt, kfb, kfa);
    if (kt >= qt) break;
    ++kt;
  }

  const float inv = 1.0f / l_i;
#pragma unroll
  for (int n = 0; n < 4; ++n) {
#pragma unroll
    for (int r = 0; r < 4; ++r) o_acc[n][r] *= inv;
    union { bf16 hx[4]; uint2 u; } ok;
#pragma unroll
    for (int r = 0; r < 4; ++r) ok.hx[r] = __float2bfloat16(o_acc[n][r]);
    // O^T lane (col=q, row=d): d = n*16 + fq*4 + r, 4 consecutive -> 8B store
    *(uint2*)&attn_out[(size_t)q_glob * DMODEL + h * HDIM + n * 16 + fq * 4] = ok.u;
  }
}

// ---------------- GEMM2: out = attn @ Wo^T, fused residual+gate ----------------
__global__ __launch_bounds__(256) void gemm_out(const bf16* __restrict__ A,
                                                const bf16* __restrict__ W,
                                                const float* __restrict__ xres,
                                                const float* __restrict__ gate,
                                                float* __restrict__ out) {
  constexpr int K = DMODEL;
  __shared__ bf16 As[128 * 32];
  __shared__ bf16 Ws[128 * 32];
  const int tid = threadIdx.x;
  const int wave = tid >> 6, lane = tid & 63;
  const int wm = wave >> 1, wn = wave & 1;
  const int m0 = blockIdx.y * 128, n0 = blockIdx.x * 128;
  const int sr = wave * 16 + (lane >> 2);
  const int sc = (lane & 3) * 8;
  const int fr = lane & 15, fq = lane >> 4;

  const f32x4 zero = {0.f, 0.f, 0.f, 0.f};
  f32x4 acc[4][4];
  for (int i = 0; i < 4; ++i)
    for (int j = 0; j < 4; ++j) acc[i][j] = zero;

  for (int kt = 0; kt < K; kt += 32) {
    __syncthreads();
    for (int i2 = 0; i2 < 2; ++i2) {
      async_copy16(A + (size_t)(m0 + i2 * 64 + sr) * K + kt + sc,
                   &As[(i2 * 64 + wave * 16) * 32]);
      async_copy16(W + (size_t)(n0 + i2 * 64 + sr) * K + kt + sc,
                   &Ws[(i2 * 64 + wave * 16) * 32]);
    }
    __syncthreads();
    short8 a[4], b[4];
    for (int i = 0; i < 4; ++i)
      a[i] = *(const short8*)&As[(wm * 64 + i * 16 + fr) * 32 + fq * 8];
    for (int j = 0; j < 4; ++j)
      b[j] = *(const short8*)&Ws[(wn * 64 + j * 16 + fr) * 32 + fq * 8];
    for (int i = 0; i < 4; ++i)
      for (int j = 0; j < 4; ++j)
        acc[i][j] = mfma_bf16(a[i], b[j], acc[i][j]);
  }

  const int col = fr, rq = fq * 4;
  for (int j = 0; j < 4; ++j) {
    const int cc = n0 + wn * 64 + j * 16 + col;
    const float g = gate[cc];
    for (int i = 0; i < 4; ++i) {
      const int base_row = m0 + wm * 64 + i * 16 + rq;
      for (int r = 0; r < 4; ++r) {
        const size_t idx = (size_t)(base_row + r) * DMODEL + cc;
        out[idx] = xres[idx] + g * acc[i][j][r];
      }
    }
  }
}

extern "C" void kernel_launch(void* const* d_in, const int* in_sizes, int n_in,
                              void* d_out, int out_size, void* d_ws, size_t ws_size,
                              hipStream_t stream) {
  const float* x    = (const float*)d_in[0];
  const float* Wqkv = (const float*)d_in[1];
  const float* Wo   = (const float*)d_in[2];
  const float* gate = (const float*)d_in[3];
  float* out = (float*)d_out;

  char* ws = (char*)d_ws;
  const size_t MB = 1024 * 1024;
  bf16* xb      = (bf16*)(ws);                 // 8 MB   (dead after gemm_qkv)
  bf16* wqkvb   = (bf16*)(ws + 8 * MB);        // 24 MB  (dead after gemm_qkv)
  bf16* wob     = (bf16*)(ws + 32 * MB);       // 8 MB
  bf16* q_ws    = (bf16*)(ws + 40 * MB);       // 8 MB
  bf16* k_ws    = (bf16*)(ws + 48 * MB);       // 8 MB
  bf16* v_ws    = (bf16*)(ws + 56 * MB);       // 8 MB
  bf16* vt_ws   = (bf16*)(ws + 8 * MB);        // aliases wqkvb
  bf16* attn_ws = (bf16*)(ws);                 // aliases xb

  cvt3_kernel<<<dim3(20480), 256, 0, stream>>>(x, xb, Wqkv, wqkvb, Wo, wob);

  gemm_qkv<<<dim3(NQKV / 128, DMODEL / 128), 256, 0, stream>>>(xb, wqkvb, q_ws, k_ws, v_ws);
  transpose_v<<<dim3(S_LEN / 64, NHEADS), 256, 0, stream>>>(v_ws, vt_ws);
  attn_kernel<<<dim3(4096), 64, 0, stream>>>(q_ws, k_ws, vt_ws, attn_ws);
  gemm_out<<<dim3(DMODEL / 128, DMODEL / 128), 256, 0, stream>>>(attn_ws, wob, x, gate, out);
}

// Round 4
// 299.514 us; speedup vs baseline: 1.6258x; 1.2603x over previous
//
#include <hip/hip_runtime.h>
#include <hip/hip_bf16.h>
#include <cstdint>
#include <cstddef>

typedef __hip_bfloat16 bf16;
typedef short short8 __attribute__((ext_vector_type(8)));
typedef float f32x4 __attribute__((ext_vector_type(4)));

#define S_LEN 2048
#define DMODEL 2048
#define NQKV 6144
#define NHEADS 32
#define HDIM 64

__device__ __forceinline__ void async_copy16(const bf16* g, bf16* l) {
  __builtin_amdgcn_global_load_lds(
      (const __attribute__((address_space(1))) void*)g,
      (__attribute__((address_space(3))) void*)l, 16, 0, 0);
}

__device__ __forceinline__ f32x4 mfma_bf16(short8 a, short8 b, f32x4 c) {
  return __builtin_amdgcn_mfma_f32_16x16x32_bf16(a, b, c, 0, 0, 0);
}

// ---------------- fused fp32 -> bf16 convert of x, Wqkv, Wo ----------------
__global__ __launch_bounds__(256) void cvt3_kernel(const float* __restrict__ sx,
                                                   bf16* __restrict__ dx,
                                                   const float* __restrict__ sw,
                                                   bf16* __restrict__ dw,
                                                   const float* __restrict__ so,
                                                   bf16* __restrict__ dov) {
  int i = blockIdx.x * 256 + threadIdx.x;
  const float* s;
  bf16* d;
  if (i < 1048576) {
    s = sx; d = dx;
  } else if (i < 4194304) {
    s = sw; d = dw; i -= 1048576;
  } else {
    s = so; d = dov; i -= 4194304;
  }
  const float4 v = ((const float4*)s)[i];
  union { bf16 h[4]; ushort4 u; } tmp;
  tmp.h[0] = __float2bfloat16(v.x);
  tmp.h[1] = __float2bfloat16(v.y);
  tmp.h[2] = __float2bfloat16(v.z);
  tmp.h[3] = __float2bfloat16(v.w);
  ((ushort4*)d)[i] = tmp.u;
}

// ---------------- GEMM1: qkv = x @ Wqkv^T, fused RoPE epilogue ----------------
__global__ __launch_bounds__(256) void gemm_qkv(const bf16* __restrict__ A,
                                                const bf16* __restrict__ W,
                                                bf16* __restrict__ q_ws,
                                                bf16* __restrict__ k_ws,
                                                bf16* __restrict__ v_ws) {
  constexpr int K = DMODEL;
  __shared__ bf16 As[128 * 32];
  __shared__ bf16 Ws[128 * 32];
  const int tid = threadIdx.x;
  const int wave = tid >> 6, lane = tid & 63;
  const int wm = wave >> 1, wn = wave & 1;
  const int m0 = blockIdx.y * 128, n0 = blockIdx.x * 128;
  const int sr = wave * 16 + (lane >> 2);
  const int sc = (lane & 3) * 8;
  const int fr = lane & 15, fq = lane >> 4;

  const f32x4 zero = {0.f, 0.f, 0.f, 0.f};
  f32x4 acc[4][4];
  for (int i = 0; i < 4; ++i)
    for (int j = 0; j < 4; ++j) acc[i][j] = zero;

  for (int kt = 0; kt < K; kt += 32) {
    __syncthreads();
    for (int i2 = 0; i2 < 2; ++i2) {
      async_copy16(A + (size_t)(m0 + i2 * 64 + sr) * K + kt + sc,
                   &As[(i2 * 64 + wave * 16) * 32]);
      async_copy16(W + (size_t)(n0 + i2 * 64 + sr) * K + kt + sc,
                   &Ws[(i2 * 64 + wave * 16) * 32]);
    }
    __syncthreads();
    short8 a[4], b[4];
    for (int i = 0; i < 4; ++i)
      a[i] = *(const short8*)&As[(wm * 64 + i * 16 + fr) * 32 + fq * 8];
    for (int j = 0; j < 4; ++j)
      b[j] = *(const short8*)&Ws[(wn * 64 + j * 16 + fr) * 32 + fq * 8];
    for (int i = 0; i < 4; ++i)
      for (int j = 0; j < 4; ++j)
        acc[i][j] = mfma_bf16(a[i], b[j], acc[i][j]);
  }

  const int colb = n0 + wn * 64;
  const int sect = colb >> 11;          // 0=q, 1=k, 2=v
  const int h = (colb & 2047) >> 6;
  const int col = fr, rq = fq * 4;

  if (sect < 2) {
    bf16* dst = ((sect == 0) ? q_ws : k_ws) + (size_t)h * S_LEN * HDIM;
    for (int jl = 0; jl < 2; ++jl) {
      const int dh = jl * 16 + col;     // pairs with dh+32 in acc tile jl+2
      const float freq = powf(10000.0f, -(float)dh * (1.0f / 32.0f));
      for (int i = 0; i < 4; ++i) {
        const int base_row = m0 + wm * 64 + i * 16 + rq;
        for (int r = 0; r < 4; ++r) {
          const int srow = base_row + r;
          float sn, cs;
          sincosf((float)srow * freq, &sn, &cs);
          const float xl = acc[i][jl][r], xh = acc[i][jl + 2][r];
          dst[(size_t)srow * HDIM + dh]      = __float2bfloat16(xl * cs - xh * sn);
          dst[(size_t)srow * HDIM + dh + 32] = __float2bfloat16(xh * cs + xl * sn);
        }
      }
    }
  } else {
    bf16* dst = v_ws + (size_t)h * S_LEN * HDIM;
    for (int j = 0; j < 4; ++j) {
      const int dh = j * 16 + col;
      for (int i = 0; i < 4; ++i) {
        const int base_row = m0 + wm * 64 + i * 16 + rq;
        for (int r = 0; r < 4; ++r)
          dst[(size_t)(base_row + r) * HDIM + dh] = __float2bfloat16(acc[i][j][r]);
      }
    }
  }
}

// ---------------- V transpose: [h][s][dh] -> [h][dh][s] ----------------
__global__ __launch_bounds__(256) void transpose_v(const bf16* __restrict__ v,
                                                   bf16* __restrict__ vt) {
  __shared__ bf16 t[64 * 66];
  const int h = blockIdx.y, s0 = blockIdx.x * 64;
  const int tid = threadIdx.x;
  const bf16* src = v + (size_t)h * S_LEN * HDIM;
  bf16* dst = vt + (size_t)h * HDIM * S_LEN;
  for (int rep = 0; rep < 16; ++rep) {
    const int idx = rep * 256 + tid;
    const int sl = idx >> 6, dh = idx & 63;
    t[sl * 66 + dh] = src[(size_t)(s0 + sl) * HDIM + dh];
  }
  __syncthreads();
  for (int rep = 0; rep < 16; ++rep) {
    const int idx = rep * 256 + tid;
    const int dh = idx >> 6, sl = idx & 63;
    dst[(size_t)dh * S_LEN + s0 + sl] = t[sl * 66 + dh];
  }
}

// ---------------- flash attention (causal) ----------------
// 256-thread blocks, grid 1024 = (qt LPT heavy-first) x 32 heads. The 4 waves
// share K/V tiles double-buffered in LDS (global_load_lds w16, one barrier per
// k-tile; prefetch issued AFTER the barrier so the next barrier's vmcnt(0)
// drain is covered by a full compute phase). XOR chunk swizzle (slot^row&7)
// replaces row padding (global_load_lds can't target padded rows) and keeps
// b128 frag reads ~2-way conflict-free.
// Transposed tile math: S^T = K·Q^T -> lane owns 16 scores of ONE query;
// softmax = in-lane reduce + 2 shfls. O^T = V^T·P^T.
__global__ __launch_bounds__(256) void attn_kernel(const bf16* __restrict__ q_ws,
                                                   const bf16* __restrict__ k_ws,
                                                   const bf16* __restrict__ vt_ws,
                                                   bf16* __restrict__ attn_out) {
  const int bid = blockIdx.x;
  const int qt = 31 - (bid >> 5);      // heavy q-tiles first (LPT)
  const int h = bid & 31;

  const int tid = threadIdx.x, wave = tid >> 6, lane = tid & 63;
  const int col = lane & 15, fq = lane >> 4;
  const int q_glob = qt * 64 + wave * 16 + col;

  __shared__ bf16 Ks[2][64 * 64];
  __shared__ bf16 Vs[2][64 * 64];
  __shared__ bf16 Pl[4][16 * 72];
  bf16* pl = Pl[wave];

  const bf16* qh = q_ws + (size_t)h * S_LEN * HDIM;
  const bf16* kh = k_ws + (size_t)h * S_LEN * HDIM;
  const bf16* vh = vt_ws + (size_t)h * HDIM * S_LEN;

  // staging geometry: lane i covers local row i/8, slot i%8; slot s of row r
  // holds global chunk s^(r&7) (8 bf16 = 16B chunks)
  const int srow = lane >> 3;
  const int slot = lane & 7;
  const int schunk = slot ^ srow;

  auto stage = [&](int kt, int buf) {
    const int k0 = kt * 64;
#pragma unroll
    for (int j = 0; j < 2; ++j) {
      const int r8 = (wave * 2 + j) * 8;   // base row of this 1KB issue
      async_copy16(kh + (size_t)(k0 + r8 + srow) * HDIM + schunk * 8,
                   &Ks[buf][r8 * 64]);
      async_copy16(vh + (size_t)(r8 + srow) * S_LEN + k0 + schunk * 8,
                   &Vs[buf][r8 * 64]);
    }
  };

  short8 qf[2];  // B operand: n=q(col), k=dh
#pragma unroll
  for (int ks = 0; ks < 2; ++ks)
    qf[ks] = *(const short8*)&qh[(size_t)q_glob * HDIM + ks * 32 + fq * 8];

  const f32x4 zero = {0.f, 0.f, 0.f, 0.f};
  f32x4 o_acc[4] = {zero, zero, zero, zero};  // O^T: col=q, row=d
  float m_i = -1e30f, l_i = 0.f;

  stage(0, 0);

  for (int kt = 0; kt <= qt; ++kt) {
    const int buf = kt & 1;
    const int k0 = kt * 64;
    __syncthreads();                 // cur tile ready; nxt buffer free
    if (kt < qt) stage(kt + 1, buf ^ 1);

    // K frags from LDS (A operand: m=key, k=dh), swizzled chunks
    short8 kf[8];
#pragma unroll
    for (int n = 0; n < 4; ++n) {
      const int row = n * 16 + col;
#pragma unroll
      for (int ks = 0; ks < 2; ++ks)
        kf[n * 2 + ks] =
            *(const short8*)&Ks[buf][row * 64 + (((ks * 4 + fq) ^ (row & 7)) * 8)];
    }
    f32x4 s_acc[4] = {zero, zero, zero, zero};
#pragma unroll
    for (int n = 0; n < 4; ++n)
#pragma unroll
      for (int ks = 0; ks < 2; ++ks)
        s_acc[n] = mfma_bf16(kf[n * 2 + ks], qf[ks], s_acc[n]);

    // V frags from LDS (A operand: m=d, k=key), issued before softmax
    short8 vf[8];
#pragma unroll
    for (int n = 0; n < 4; ++n) {
      const int row = n * 16 + col;
#pragma unroll
      for (int ks = 0; ks < 2; ++ks)
        vf[n * 2 + ks] =
            *(const short8*)&Vs[buf][row * 64 + (((ks * 4 + fq) ^ (row & 7)) * 8)];
    }

    // causal mask (bound tile only): key = k0 + n*16 + fq*4 + r
    if (kt == qt) {
#pragma unroll
      for (int n = 0; n < 4; ++n)
#pragma unroll
        for (int r = 0; r < 4; ++r)
          if (k0 + n * 16 + fq * 4 + r > q_glob) s_acc[n][r] = -1e30f;
    }

    float vmax = -1e30f;
#pragma unroll
    for (int n = 0; n < 4; ++n)
#pragma unroll
      for (int r = 0; r < 4; ++r) vmax = fmaxf(vmax, s_acc[n][r]);
    vmax = fmaxf(vmax, __shfl_xor(vmax, 16, 64));
    vmax = fmaxf(vmax, __shfl_xor(vmax, 32, 64));
    const float mnew = fmaxf(m_i, vmax);
    const float alpha = __expf((m_i - mnew) * 0.125f);
    m_i = mnew;

    float rs = 0.f;
#pragma unroll
    for (int n = 0; n < 4; ++n)
#pragma unroll
      for (int r = 0; r < 4; ++r) {
        const float p = __expf((s_acc[n][r] - mnew) * 0.125f);
        s_acc[n][r] = p;
        rs += p;
      }
    rs += __shfl_xor(rs, 16, 64);
    rs += __shfl_xor(rs, 32, 64);
    l_i = l_i * alpha + rs;

#pragma unroll
    for (int n = 0; n < 4; ++n)
#pragma unroll
      for (int r = 0; r < 4; ++r) o_acc[n][r] *= alpha;

    // P^T -> LDS (wave-private, padded stride 72): one b64 write per n
#pragma unroll
    for (int n = 0; n < 4; ++n) {
      union { bf16 hx[4]; uint2 u; } pk;
#pragma unroll
      for (int r = 0; r < 4; ++r) pk.hx[r] = __float2bfloat16(s_acc[n][r]);
      *(uint2*)&pl[col * 72 + n * 16 + fq * 4] = pk.u;
    }
    short8 pa[2];  // B operand: k=key, n=q(col)
#pragma unroll
    for (int ks = 0; ks < 2; ++ks)
      pa[ks] = *(const short8*)&pl[col * 72 + ks * 32 + fq * 8];

#pragma unroll
    for (int n = 0; n < 4; ++n)
#pragma unroll
      for (int ks = 0; ks < 2; ++ks)
        o_acc[n] = mfma_bf16(vf[n * 2 + ks], pa[ks], o_acc[n]);
  }

  const float inv = 1.0f / l_i;
#pragma unroll
  for (int n = 0; n < 4; ++n) {
#pragma unroll
    for (int r = 0; r < 4; ++r) o_acc[n][r] *= inv;
    union { bf16 hx[4]; uint2 u; } ok;
#pragma unroll
    for (int r = 0; r < 4; ++r) ok.hx[r] = __float2bfloat16(o_acc[n][r]);
    *(uint2*)&attn_out[(size_t)q_glob * DMODEL + h * HDIM + n * 16 + fq * 4] = ok.u;
  }
}

// ---------------- GEMM2: out = attn @ Wo^T, fused residual+gate ----------------
__global__ __launch_bounds__(256) void gemm_out(const bf16* __restrict__ A,
                                                const bf16* __restrict__ W,
                                                const float* __restrict__ xres,
                                                const float* __restrict__ gate,
                                                float* __restrict__ out) {
  constexpr int K = DMODEL;
  __shared__ bf16 As[128 * 32];
  __shared__ bf16 Ws[128 * 32];
  const int tid = threadIdx.x;
  const int wave = tid >> 6, lane = tid & 63;
  const int wm = wave >> 1, wn = wave & 1;
  const int m0 = blockIdx.y * 128, n0 = blockIdx.x * 128;
  const int sr = wave * 16 + (lane >> 2);
  const int sc = (lane & 3) * 8;
  const int fr = lane & 15, fq = lane >> 4;

  const f32x4 zero = {0.f, 0.f, 0.f, 0.f};
  f32x4 acc[4][4];
  for (int i = 0; i < 4; ++i)
    for (int j = 0; j < 4; ++j) acc[i][j] = zero;

  for (int kt = 0; kt < K; kt += 32) {
    __syncthreads();
    for (int i2 = 0; i2 < 2; ++i2) {
      async_copy16(A + (size_t)(m0 + i2 * 64 + sr) * K + kt + sc,
                   &As[(i2 * 64 + wave * 16) * 32]);
      async_copy16(W + (size_t)(n0 + i2 * 64 + sr) * K + kt + sc,
                   &Ws[(i2 * 64 + wave * 16) * 32]);
    }
    __syncthreads();
    short8 a[4], b[4];
    for (int i = 0; i < 4; ++i)
      a[i] = *(const short8*)&As[(wm * 64 + i * 16 + fr) * 32 + fq * 8];
    for (int j = 0; j < 4; ++j)
      b[j] = *(const short8*)&Ws[(wn * 64 + j * 16 + fr) * 32 + fq * 8];
    for (int i = 0; i < 4; ++i)
      for (int j = 0; j < 4; ++j)
        acc[i][j] = mfma_bf16(a[i], b[j], acc[i][j]);
  }

  const int col = fr, rq = fq * 4;
  for (int j = 0; j < 4; ++j) {
    const int cc = n0 + wn * 64 + j * 16 + col;
    const float g = gate[cc];
    for (int i = 0; i < 4; ++i) {
      const int base_row = m0 + wm * 64 + i * 16 + rq;
      for (int r = 0; r < 4; ++r) {
        const size_t idx = (size_t)(base_row + r) * DMODEL + cc;
        out[idx] = xres[idx] + g * acc[i][j][r];
      }
    }
  }
}

extern "C" void kernel_launch(void* const* d_in, const int* in_sizes, int n_in,
                              void* d_out, int out_size, void* d_ws, size_t ws_size,
                              hipStream_t stream) {
  const float* x    = (const float*)d_in[0];
  const float* Wqkv = (const float*)d_in[1];
  const float* Wo   = (const float*)d_in[2];
  const float* gate = (const float*)d_in[3];
  float* out = (float*)d_out;

  char* ws = (char*)d_ws;
  const size_t MB = 1024 * 1024;
  bf16* xb      = (bf16*)(ws);                 // 8 MB   (dead after gemm_qkv)
  bf16* wqkvb   = (bf16*)(ws + 8 * MB);        // 24 MB  (dead after gemm_qkv)
  bf16* wob     = (bf16*)(ws + 32 * MB);       // 8 MB
  bf16* q_ws    = (bf16*)(ws + 40 * MB);       // 8 MB
  bf16* k_ws    = (bf16*)(ws + 48 * MB);       // 8 MB
  bf16* v_ws    = (bf16*)(ws + 56 * MB);       // 8 MB
  bf16* vt_ws   = (bf16*)(ws + 8 * MB);        // aliases wqkvb
  bf16* attn_ws = (bf16*)(ws);                 // aliases xb

  cvt3_kernel<<<dim3(20480), 256, 0, stream>>>(x, xb, Wqkv, wqkvb, Wo, wob);

  gemm_qkv<<<dim3(NQKV / 128, DMODEL / 128), 256, 0, stream>>>(xb, wqkvb, q_ws, k_ws, v_ws);
  transpose_v<<<dim3(S_LEN / 64, NHEADS), 256, 0, stream>>>(v_ws, vt_ws);
  attn_kernel<<<dim3(1024), 256, 0, stream>>>(q_ws, k_ws, vt_ws, attn_ws);
  gemm_out<<<dim3(DMODEL / 128, DMODEL / 128), 256, 0, stream>>>(attn_ws, wob, x, gate, out);
}

// Round 5
// 259.254 us; speedup vs baseline: 1.8782x; 1.1553x over previous
//
#include <hip/hip_runtime.h>
#include <hip/hip_bf16.h>
#include <cstdint>
#include <cstddef>

typedef __hip_bfloat16 bf16;
typedef short short8 __attribute__((ext_vector_type(8)));
typedef float f32x4 __attribute__((ext_vector_type(4)));

#define S_LEN 2048
#define DMODEL 2048
#define NQKV 6144
#define NHEADS 32
#define HDIM 64
// log2(10000)/32
#define ROPE_L2 0.4152410118609203f

__device__ __forceinline__ void async_copy16(const bf16* g, bf16* l) {
  __builtin_amdgcn_global_load_lds(
      (const __attribute__((address_space(1))) void*)g,
      (__attribute__((address_space(3))) void*)l, 16, 0, 0);
}

__device__ __forceinline__ f32x4 mfma_bf16(short8 a, short8 b, f32x4 c) {
  return __builtin_amdgcn_mfma_f32_16x16x32_bf16(a, b, c, 0, 0, 0);
}

// ---------------- fused fp32 -> bf16 convert of x, Wqkv, Wo ----------------
__global__ __launch_bounds__(256) void cvt3_kernel(const float* __restrict__ sx,
                                                   bf16* __restrict__ dx,
                                                   const float* __restrict__ sw,
                                                   bf16* __restrict__ dw,
                                                   const float* __restrict__ so,
                                                   bf16* __restrict__ dov) {
  int i = blockIdx.x * 256 + threadIdx.x;
  const float* s;
  bf16* d;
  if (i < 1048576) {
    s = sx; d = dx;
  } else if (i < 4194304) {
    s = sw; d = dw; i -= 1048576;
  } else {
    s = so; d = dov; i -= 4194304;
  }
  const float4 v = ((const float4*)s)[i];
  union { bf16 h[4]; ushort4 u; } tmp;
  tmp.h[0] = __float2bfloat16(v.x);
  tmp.h[1] = __float2bfloat16(v.y);
  tmp.h[2] = __float2bfloat16(v.z);
  tmp.h[3] = __float2bfloat16(v.w);
  ((ushort4*)d)[i] = tmp.u;
}

// ---------------- GEMM1: qkv = x @ Wqkv^T, fused RoPE epilogue ----------------
// XOR-swizzled LDS (slot = chunk ^ ((row>>1)&3)) -> conflict-free b128 frag reads.
// q/k epilogue: hw __sincosf RoPE, repack via per-wave LDS tile -> 16B stores.
// v epilogue: written directly transposed [h][dh][s] (uint2 stores).
__global__ __launch_bounds__(256) void gemm_qkv(const bf16* __restrict__ A,
                                                const bf16* __restrict__ W,
                                                bf16* __restrict__ q_ws,
                                                bf16* __restrict__ k_ws,
                                                bf16* __restrict__ v_ws) {
  constexpr int K = DMODEL;
  __shared__ bf16 smem[8192];          // As = smem[0:4096], Ws = smem[4096:8192]
  const int tid = threadIdx.x;
  const int wave = tid >> 6, lane = tid & 63;
  const int wm = wave >> 1, wn = wave & 1;
  const int m0 = blockIdx.y * 128, n0 = blockIdx.x * 128;
  const int sr = wave * 16 + (lane >> 2);
  const int swc = (((lane & 3) ^ ((lane >> 3) & 3)) * 8);  // swizzled src chunk
  const int fr = lane & 15, fq = lane >> 4;
  const int xw = (fr >> 1) & 3;        // frag-read swizzle
  const int rdc = ((fq ^ xw) * 8);

  const f32x4 zero = {0.f, 0.f, 0.f, 0.f};
  f32x4 acc[4][4];
  for (int i = 0; i < 4; ++i)
    for (int j = 0; j < 4; ++j) acc[i][j] = zero;

  for (int kt = 0; kt < K; kt += 32) {
    __syncthreads();
    for (int i2 = 0; i2 < 2; ++i2) {
      async_copy16(A + (size_t)(m0 + i2 * 64 + sr) * K + kt + swc,
                   &smem[(i2 * 64 + wave * 16) * 32]);
      async_copy16(W + (size_t)(n0 + i2 * 64 + sr) * K + kt + swc,
                   &smem[4096 + (i2 * 64 + wave * 16) * 32]);
    }
    __syncthreads();
    short8 a[4], b[4];
    for (int i = 0; i < 4; ++i)
      a[i] = *(const short8*)&smem[(wm * 64 + i * 16 + fr) * 32 + rdc];
    for (int j = 0; j < 4; ++j)
      b[j] = *(const short8*)&smem[4096 + (wn * 64 + j * 16 + fr) * 32 + rdc];
    for (int i = 0; i < 4; ++i)
      for (int j = 0; j < 4; ++j)
        acc[i][j] = mfma_bf16(a[i], b[j], acc[i][j]);
  }

  const int colb = n0 + wn * 64;
  const int sect = colb >> 11;          // 0=q, 1=k, 2=v (block-uniform)
  const int h = (colb & 2047) >> 6;
  const int col = fr, rq = fq * 4;

  if (sect < 2) {
    bf16* dst = ((sect == 0) ? q_ws : k_ws) + (size_t)h * S_LEN * HDIM;
    // per-wave repack tile: 16 rows x stride 72 (16B-aligned rows)
    bf16* rep = smem + wave * 1152;
    const float f0 = exp2f(-(float)col * ROPE_L2);
    const float f1 = exp2f(-(float)(16 + col) * ROPE_L2);
    __syncthreads();                    // k-loop LDS reads done before overwrite
    for (int i = 0; i < 4; ++i) {
      const int base_s = m0 + wm * 64 + i * 16;
#pragma unroll
      for (int jl = 0; jl < 2; ++jl) {
        const int dh = jl * 16 + col;
        const float fr_ = (jl == 0) ? f0 : f1;
#pragma unroll
        for (int r = 0; r < 4; ++r) {
          const int srow = base_s + rq + r;
          float sn, cs;
          __sincosf((float)srow * fr_, &sn, &cs);
          const float xl = acc[i][jl][r], xh = acc[i][jl + 2][r];
          rep[(rq + r) * 72 + dh]      = __float2bfloat16(xl * cs - xh * sn);
          rep[(rq + r) * 72 + dh + 32] = __float2bfloat16(xh * cs + xl * sn);
        }
      }
      // coalesced write-out: 2 passes x (8 rows x 128B contiguous)
#pragma unroll
      for (int p = 0; p < 2; ++p) {
        const int rr = p * 8 + (lane >> 3), ch = lane & 7;
        const uint4 vv = *(const uint4*)&rep[rr * 72 + ch * 8];
        *(uint4*)&dst[(size_t)(base_s + rr) * HDIM + ch * 8] = vv;
      }
    }
  } else {
    // V stored transposed: [h][dh][s]; lane's 4 r-values are consecutive s
    bf16* dst = v_ws + (size_t)h * HDIM * S_LEN;
    for (int j = 0; j < 4; ++j) {
      const int dh = j * 16 + col;
      for (int i = 0; i < 4; ++i) {
        const int s0 = m0 + wm * 64 + i * 16 + rq;
        union { bf16 hx[4]; uint2 u; } vk;
#pragma unroll
        for (int r = 0; r < 4; ++r) vk.hx[r] = __float2bfloat16(acc[i][j][r]);
        *(uint2*)&dst[(size_t)dh * S_LEN + s0] = vk.u;
      }
    }
  }
}

// ---------------- flash attention (causal) ----------------
// 256-thread blocks, grid 1024 = (qt LPT heavy-first) x 32 heads. 4 waves share
// K/V tiles double-buffered in LDS (global_load_lds w16, one barrier per k-tile).
// XOR chunk swizzle on staging. Transposed tile math: S^T = K·Q^T; O^T = V^T·P^T.
__global__ __launch_bounds__(256) void attn_kernel(const bf16* __restrict__ q_ws,
                                                   const bf16* __restrict__ k_ws,
                                                   const bf16* __restrict__ vt_ws,
                                                   bf16* __restrict__ attn_out) {
  const int bid = blockIdx.x;
  const int qt = 31 - (bid >> 5);      // heavy q-tiles first (LPT)
  const int h = bid & 31;

  const int tid = threadIdx.x, wave = tid >> 6, lane = tid & 63;
  const int col = lane & 15, fq = lane >> 4;
  const int q_glob = qt * 64 + wave * 16 + col;

  __shared__ bf16 Ks[2][64 * 64];
  __shared__ bf16 Vs[2][64 * 64];
  __shared__ bf16 Pl[4][16 * 72];
  bf16* pl = Pl[wave];

  const bf16* qh = q_ws + (size_t)h * S_LEN * HDIM;
  const bf16* kh = k_ws + (size_t)h * S_LEN * HDIM;
  const bf16* vh = vt_ws + (size_t)h * HDIM * S_LEN;

  const int srow = lane >> 3;
  const int slot = lane & 7;
  const int schunk = slot ^ srow;

  auto stage = [&](int kt, int buf) {
    const int k0 = kt * 64;
#pragma unroll
    for (int j = 0; j < 2; ++j) {
      const int r8 = (wave * 2 + j) * 8;
      async_copy16(kh + (size_t)(k0 + r8 + srow) * HDIM + schunk * 8,
                   &Ks[buf][r8 * 64]);
      async_copy16(vh + (size_t)(r8 + srow) * S_LEN + k0 + schunk * 8,
                   &Vs[buf][r8 * 64]);
    }
  };

  short8 qf[2];
#pragma unroll
  for (int ks = 0; ks < 2; ++ks)
    qf[ks] = *(const short8*)&qh[(size_t)q_glob * HDIM + ks * 32 + fq * 8];

  const f32x4 zero = {0.f, 0.f, 0.f, 0.f};
  f32x4 o_acc[4] = {zero, zero, zero, zero};
  float m_i = -1e30f, l_i = 0.f;

  stage(0, 0);

  for (int kt = 0; kt <= qt; ++kt) {
    const int buf = kt & 1;
    const int k0 = kt * 64;
    __syncthreads();
    if (kt < qt) stage(kt + 1, buf ^ 1);

    short8 kf[8];
#pragma unroll
    for (int n = 0; n < 4; ++n) {
      const int row = n * 16 + col;
#pragma unroll
      for (int ks = 0; ks < 2; ++ks)
        kf[n * 2 + ks] =
            *(const short8*)&Ks[buf][row * 64 + (((ks * 4 + fq) ^ (row & 7)) * 8)];
    }
    f32x4 s_acc[4] = {zero, zero, zero, zero};
#pragma unroll
    for (int n = 0; n < 4; ++n)
#pragma unroll
      for (int ks = 0; ks < 2; ++ks)
        s_acc[n] = mfma_bf16(kf[n * 2 + ks], qf[ks], s_acc[n]);

    short8 vf[8];
#pragma unroll
    for (int n = 0; n < 4; ++n) {
      const int row = n * 16 + col;
#pragma unroll
      for (int ks = 0; ks < 2; ++ks)
        vf[n * 2 + ks] =
            *(const short8*)&Vs[buf][row * 64 + (((ks * 4 + fq) ^ (row & 7)) * 8)];
    }

    if (kt == qt) {
#pragma unroll
      for (int n = 0; n < 4; ++n)
#pragma unroll
        for (int r = 0; r < 4; ++r)
          if (k0 + n * 16 + fq * 4 + r > q_glob) s_acc[n][r] = -1e30f;
    }

    float vmax = -1e30f;
#pragma unroll
    for (int n = 0; n < 4; ++n)
#pragma unroll
      for (int r = 0; r < 4; ++r) vmax = fmaxf(vmax, s_acc[n][r]);
    vmax = fmaxf(vmax, __shfl_xor(vmax, 16, 64));
    vmax = fmaxf(vmax, __shfl_xor(vmax, 32, 64));
    const float mnew = fmaxf(m_i, vmax);
    const float alpha = __expf((m_i - mnew) * 0.125f);
    m_i = mnew;

    float rs = 0.f;
#pragma unroll
    for (int n = 0; n < 4; ++n)
#pragma unroll
      for (int r = 0; r < 4; ++r) {
        const float p = __expf((s_acc[n][r] - mnew) * 0.125f);
        s_acc[n][r] = p;
        rs += p;
      }
    rs += __shfl_xor(rs, 16, 64);
    rs += __shfl_xor(rs, 32, 64);
    l_i = l_i * alpha + rs;

#pragma unroll
    for (int n = 0; n < 4; ++n)
#pragma unroll
      for (int r = 0; r < 4; ++r) o_acc[n][r] *= alpha;

#pragma unroll
    for (int n = 0; n < 4; ++n) {
      union { bf16 hx[4]; uint2 u; } pk;
#pragma unroll
      for (int r = 0; r < 4; ++r) pk.hx[r] = __float2bfloat16(s_acc[n][r]);
      *(uint2*)&pl[col * 72 + n * 16 + fq * 4] = pk.u;
    }
    short8 pa[2];
#pragma unroll
    for (int ks = 0; ks < 2; ++ks)
      pa[ks] = *(const short8*)&pl[col * 72 + ks * 32 + fq * 8];

#pragma unroll
    for (int n = 0; n < 4; ++n)
#pragma unroll
      for (int ks = 0; ks < 2; ++ks)
        o_acc[n] = mfma_bf16(vf[n * 2 + ks], pa[ks], o_acc[n]);
  }

  const float inv = 1.0f / l_i;
#pragma unroll
  for (int n = 0; n < 4; ++n) {
#pragma unroll
    for (int r = 0; r < 4; ++r) o_acc[n][r] *= inv;
    union { bf16 hx[4]; uint2 u; } ok;
#pragma unroll
    for (int r = 0; r < 4; ++r) ok.hx[r] = __float2bfloat16(o_acc[n][r]);
    *(uint2*)&attn_out[(size_t)q_glob * DMODEL + h * HDIM + n * 16 + fq * 4] = ok.u;
  }
}

// ---------------- GEMM2: out = attn @ Wo^T, fused residual+gate ----------------
__global__ __launch_bounds__(256) void gemm_out(const bf16* __restrict__ A,
                                                const bf16* __restrict__ W,
                                                const float* __restrict__ xres,
                                                const float* __restrict__ gate,
                                                float* __restrict__ out) {
  constexpr int K = DMODEL;
  __shared__ bf16 As[128 * 32];
  __shared__ bf16 Ws[128 * 32];
  const int tid = threadIdx.x;
  const int wave = tid >> 6, lane = tid & 63;
  const int wm = wave >> 1, wn = wave & 1;
  const int m0 = blockIdx.y * 128, n0 = blockIdx.x * 128;
  const int sr = wave * 16 + (lane >> 2);
  const int swc = (((lane & 3) ^ ((lane >> 3) & 3)) * 8);
  const int fr = lane & 15, fq = lane >> 4;
  const int rdc = ((fq ^ ((fr >> 1) & 3)) * 8);

  const f32x4 zero = {0.f, 0.f, 0.f, 0.f};
  f32x4 acc[4][4];
  for (int i = 0; i < 4; ++i)
    for (int j = 0; j < 4; ++j) acc[i][j] = zero;

  for (int kt = 0; kt < K; kt += 32) {
    __syncthreads();
    for (int i2 = 0; i2 < 2; ++i2) {
      async_copy16(A + (size_t)(m0 + i2 * 64 + sr) * K + kt + swc,
                   &As[(i2 * 64 + wave * 16) * 32]);
      async_copy16(W + (size_t)(n0 + i2 * 64 + sr) * K + kt + swc,
                   &Ws[(i2 * 64 + wave * 16) * 32]);
    }
    __syncthreads();
    short8 a[4], b[4];
    for (int i = 0; i < 4; ++i)
      a[i] = *(const short8*)&As[(wm * 64 + i * 16 + fr) * 32 + rdc];
    for (int j = 0; j < 4; ++j)
      b[j] = *(const short8*)&Ws[(wn * 64 + j * 16 + fr) * 32 + rdc];
    for (int i = 0; i < 4; ++i)
      for (int j = 0; j < 4; ++j)
        acc[i][j] = mfma_bf16(a[i], b[j], acc[i][j]);
  }

  const int col = fr, rq = fq * 4;
  for (int j = 0; j < 4; ++j) {
    const int cc = n0 + wn * 64 + j * 16 + col;
    const float g = gate[cc];
    for (int i = 0; i < 4; ++i) {
      const int base_row = m0 + wm * 64 + i * 16 + rq;
      for (int r = 0; r < 4; ++r) {
        const size_t idx = (size_t)(base_row + r) * DMODEL + cc;
        out[idx] = xres[idx] + g * acc[i][j][r];
      }
    }
  }
}

extern "C" void kernel_launch(void* const* d_in, const int* in_sizes, int n_in,
                              void* d_out, int out_size, void* d_ws, size_t ws_size,
                              hipStream_t stream) {
  const float* x    = (const float*)d_in[0];
  const float* Wqkv = (const float*)d_in[1];
  const float* Wo   = (const float*)d_in[2];
  const float* gate = (const float*)d_in[3];
  float* out = (float*)d_out;

  char* ws = (char*)d_ws;
  const size_t MB = 1024 * 1024;
  bf16* xb      = (bf16*)(ws);                 // 8 MB   (dead after gemm_qkv)
  bf16* wqkvb   = (bf16*)(ws + 8 * MB);        // 24 MB  (dead after gemm_qkv)
  bf16* wob     = (bf16*)(ws + 32 * MB);       // 8 MB
  bf16* q_ws    = (bf16*)(ws + 40 * MB);       // 8 MB  [h][s][dh]
  bf16* k_ws    = (bf16*)(ws + 48 * MB);       // 8 MB  [h][s][dh]
  bf16* v_ws    = (bf16*)(ws + 56 * MB);       // 8 MB  [h][dh][s] (pre-transposed)
  bf16* attn_ws = (bf16*)(ws);                 // aliases xb

  cvt3_kernel<<<dim3(20480), 256, 0, stream>>>(x, xb, Wqkv, wqkvb, Wo, wob);

  gemm_qkv<<<dim3(NQKV / 128, DMODEL / 128), 256, 0, stream>>>(xb, wqkvb, q_ws, k_ws, v_ws);
  attn_kernel<<<dim3(1024), 256, 0, stream>>>(q_ws, k_ws, v_ws, attn_ws);
  gemm_out<<<dim3(DMODEL / 128, DMODEL / 128), 256, 0, stream>>>(attn_ws, wob, x, gate, out);
}

// Round 7
// 253.130 us; speedup vs baseline: 1.9237x; 1.0242x over previous
//
#include <hip/hip_runtime.h>
#include <hip/hip_bf16.h>
#include <cstdint>
#include <cstddef>

typedef __hip_bfloat16 bf16;
typedef short short8 __attribute__((ext_vector_type(8)));
typedef float f32x4 __attribute__((ext_vector_type(4)));

#define S_LEN 2048
#define DMODEL 2048
#define NQKV 6144
#define NHEADS 32
#define HDIM 64
// log2(10000)/32
#define ROPE_L2 0.4152410118609203f

__device__ __forceinline__ void async_copy16(const bf16* g, bf16* l) {
  __builtin_amdgcn_global_load_lds(
      (const __attribute__((address_space(1))) void*)g,
      (__attribute__((address_space(3))) void*)l, 16, 0, 0);
}

__device__ __forceinline__ f32x4 mfma_bf16(short8 a, short8 b, f32x4 c) {
  return __builtin_amdgcn_mfma_f32_16x16x32_bf16(a, b, c, 0, 0, 0);
}

// ---------------- fused fp32 -> bf16 convert of x, Wqkv, Wo ----------------
__global__ __launch_bounds__(256) void cvt3_kernel(const float* __restrict__ sx,
                                                   bf16* __restrict__ dx,
                                                   const float* __restrict__ sw,
                                                   bf16* __restrict__ dw,
                                                   const float* __restrict__ so,
                                                   bf16* __restrict__ dov) {
  int i = blockIdx.x * 256 + threadIdx.x;
  const float* s;
  bf16* d;
  if (i < 1048576) {
    s = sx; d = dx;
  } else if (i < 4194304) {
    s = sw; d = dw; i -= 1048576;
  } else {
    s = so; d = dov; i -= 4194304;
  }
  const float4 v = ((const float4*)s)[i];
  union { bf16 h[4]; ushort4 u; } tmp;
  tmp.h[0] = __float2bfloat16(v.x);
  tmp.h[1] = __float2bfloat16(v.y);
  tmp.h[2] = __float2bfloat16(v.z);
  tmp.h[3] = __float2bfloat16(v.w);
  ((ushort4*)d)[i] = tmp.u;
}

// ---------------- GEMM1: qkv = x @ Wqkv^T, fused RoPE epilogue ----------------
__global__ __launch_bounds__(256) void gemm_qkv(const bf16* __restrict__ A,
                                                const bf16* __restrict__ W,
                                                bf16* __restrict__ q_ws,
                                                bf16* __restrict__ k_ws,
                                                bf16* __restrict__ v_ws) {
  constexpr int K = DMODEL;
  __shared__ bf16 smem[8192];          // As = smem[0:4096], Ws = smem[4096:8192]
  const int tid = threadIdx.x;
  const int wave = tid >> 6, lane = tid & 63;
  const int wm = wave >> 1, wn = wave & 1;
  const int m0 = blockIdx.y * 128, n0 = blockIdx.x * 128;
  const int sr = wave * 16 + (lane >> 2);
  const int swc = (((lane & 3) ^ ((lane >> 3) & 3)) * 8);  // swizzled src chunk
  const int fr = lane & 15, fq = lane >> 4;
  const int rdc = ((fq ^ ((fr >> 1) & 3)) * 8);

  const f32x4 zero = {0.f, 0.f, 0.f, 0.f};
  f32x4 acc[4][4];
  for (int i = 0; i < 4; ++i)
    for (int j = 0; j < 4; ++j) acc[i][j] = zero;

  for (int kt = 0; kt < K; kt += 32) {
    __syncthreads();
    for (int i2 = 0; i2 < 2; ++i2) {
      async_copy16(A + (size_t)(m0 + i2 * 64 + sr) * K + kt + swc,
                   &smem[(i2 * 64 + wave * 16) * 32]);
      async_copy16(W + (size_t)(n0 + i2 * 64 + sr) * K + kt + swc,
                   &smem[4096 + (i2 * 64 + wave * 16) * 32]);
    }
    __syncthreads();
    short8 a[4], b[4];
    for (int i = 0; i < 4; ++i)
      a[i] = *(const short8*)&smem[(wm * 64 + i * 16 + fr) * 32 + rdc];
    for (int j = 0; j < 4; ++j)
      b[j] = *(const short8*)&smem[4096 + (wn * 64 + j * 16 + fr) * 32 + rdc];
    for (int i = 0; i < 4; ++i)
      for (int j = 0; j < 4; ++j)
        acc[i][j] = mfma_bf16(a[i], b[j], acc[i][j]);
  }

  const int colb = n0 + wn * 64;
  const int sect = colb >> 11;          // 0=q, 1=k, 2=v (block-uniform)
  const int h = (colb & 2047) >> 6;
  const int col = fr, rq = fq * 4;

  if (sect < 2) {
    bf16* dst = ((sect == 0) ? q_ws : k_ws) + (size_t)h * S_LEN * HDIM;
    bf16* rep = smem + wave * 1152;     // 16 rows x stride 72 (16B-aligned)
    const float f0 = exp2f(-(float)col * ROPE_L2);
    const float f1 = exp2f(-(float)(16 + col) * ROPE_L2);
    __syncthreads();
    for (int i = 0; i < 4; ++i) {
      const int base_s = m0 + wm * 64 + i * 16;
#pragma unroll
      for (int jl = 0; jl < 2; ++jl) {
        const int dh = jl * 16 + col;
        const float fr_ = (jl == 0) ? f0 : f1;
#pragma unroll
        for (int r = 0; r < 4; ++r) {
          const int srow = base_s + rq + r;
          float sn, cs;
          __sincosf((float)srow * fr_, &sn, &cs);
          const float xl = acc[i][jl][r], xh = acc[i][jl + 2][r];
          rep[(rq + r) * 72 + dh]      = __float2bfloat16(xl * cs - xh * sn);
          rep[(rq + r) * 72 + dh + 32] = __float2bfloat16(xh * cs + xl * sn);
        }
      }
#pragma unroll
      for (int p = 0; p < 2; ++p) {
        const int rr = p * 8 + (lane >> 3), ch = lane & 7;
        const uint4 vv = *(const uint4*)&rep[rr * 72 + ch * 8];
        *(uint4*)&dst[(size_t)(base_s + rr) * HDIM + ch * 8] = vv;
      }
    }
  } else {
    // V stored transposed: [h][dh][s]
    bf16* dst = v_ws + (size_t)h * HDIM * S_LEN;
    for (int j = 0; j < 4; ++j) {
      const int dh = j * 16 + col;
      for (int i = 0; i < 4; ++i) {
        const int s0 = m0 + wm * 64 + i * 16 + rq;
        union { bf16 hx[4]; uint2 u; } vk;
#pragma unroll
        for (int r = 0; r < 4; ++r) vk.hx[r] = __float2bfloat16(acc[i][j][r]);
        *(uint2*)&dst[(size_t)dh * S_LEN + s0] = vk.u;
      }
    }
  }
}

// ---------------- flash attention (causal) — proven R5 structure ----------------
// 256-thread blocks, grid 1024 = (qt LPT heavy-first) x 32 heads. 4 waves share
// K/V tiles double-buffered in LDS (global_load_lds w16, one barrier per k-tile).
// XOR chunk swizzle on staging. Transposed tile math: S^T = K·Q^T; O^T = V^T·P^T.
__global__ __launch_bounds__(256) void attn_kernel(const bf16* __restrict__ q_ws,
                                                   const bf16* __restrict__ k_ws,
                                                   const bf16* __restrict__ vt_ws,
                                                   bf16* __restrict__ attn_out) {
  const int bid = blockIdx.x;
  const int qt = 31 - (bid >> 5);      // heavy q-tiles first (LPT)
  const int h = bid & 31;

  const int tid = threadIdx.x, wave = tid >> 6, lane = tid & 63;
  const int col = lane & 15, fq = lane >> 4;
  const int q_glob = qt * 64 + wave * 16 + col;

  __shared__ bf16 Ks[2][64 * 64];
  __shared__ bf16 Vs[2][64 * 64];
  __shared__ bf16 Pl[4][16 * 72];
  bf16* pl = Pl[wave];

  const bf16* qh = q_ws + (size_t)h * S_LEN * HDIM;
  const bf16* kh = k_ws + (size_t)h * S_LEN * HDIM;
  const bf16* vh = vt_ws + (size_t)h * HDIM * S_LEN;

  const int srow = lane >> 3;
  const int slot = lane & 7;
  const int schunk = slot ^ srow;

  auto stage = [&](int kt, int buf) {
    const int k0 = kt * 64;
#pragma unroll
    for (int j = 0; j < 2; ++j) {
      const int r8 = (wave * 2 + j) * 8;
      async_copy16(kh + (size_t)(k0 + r8 + srow) * HDIM + schunk * 8,
                   &Ks[buf][r8 * 64]);
      async_copy16(vh + (size_t)(r8 + srow) * S_LEN + k0 + schunk * 8,
                   &Vs[buf][r8 * 64]);
    }
  };

  short8 qf[2];
#pragma unroll
  for (int ks = 0; ks < 2; ++ks)
    qf[ks] = *(const short8*)&qh[(size_t)q_glob * HDIM + ks * 32 + fq * 8];

  const f32x4 zero = {0.f, 0.f, 0.f, 0.f};
  f32x4 o_acc[4] = {zero, zero, zero, zero};
  float m_i = -1e30f, l_i = 0.f;

  stage(0, 0);

  for (int kt = 0; kt <= qt; ++kt) {
    const int buf = kt & 1;
    const int k0 = kt * 64;
    __syncthreads();
    if (kt < qt) stage(kt + 1, buf ^ 1);

    short8 kf[8];
#pragma unroll
    for (int n = 0; n < 4; ++n) {
      const int row = n * 16 + col;
#pragma unroll
      for (int ks = 0; ks < 2; ++ks)
        kf[n * 2 + ks] =
            *(const short8*)&Ks[buf][row * 64 + (((ks * 4 + fq) ^ (row & 7)) * 8)];
    }
    f32x4 s_acc[4] = {zero, zero, zero, zero};
#pragma unroll
    for (int n = 0; n < 4; ++n)
#pragma unroll
      for (int ks = 0; ks < 2; ++ks)
        s_acc[n] = mfma_bf16(kf[n * 2 + ks], qf[ks], s_acc[n]);

    short8 vf[8];
#pragma unroll
    for (int n = 0; n < 4; ++n) {
      const int row = n * 16 + col;
#pragma unroll
      for (int ks = 0; ks < 2; ++ks)
        vf[n * 2 + ks] =
            *(const short8*)&Vs[buf][row * 64 + (((ks * 4 + fq) ^ (row & 7)) * 8)];
    }

    if (kt == qt) {
#pragma unroll
      for (int n = 0; n < 4; ++n)
#pragma unroll
        for (int r = 0; r < 4; ++r)
          if (k0 + n * 16 + fq * 4 + r > q_glob) s_acc[n][r] = -1e30f;
    }

    float vmax = -1e30f;
#pragma unroll
    for (int n = 0; n < 4; ++n)
#pragma unroll
      for (int r = 0; r < 4; ++r) vmax = fmaxf(vmax, s_acc[n][r]);
    vmax = fmaxf(vmax, __shfl_xor(vmax, 16, 64));
    vmax = fmaxf(vmax, __shfl_xor(vmax, 32, 64));
    const float mnew = fmaxf(m_i, vmax);
    const float alpha = __expf((m_i - mnew) * 0.125f);
    m_i = mnew;

    float rs = 0.f;
#pragma unroll
    for (int n = 0; n < 4; ++n)
#pragma unroll
      for (int r = 0; r < 4; ++r) {
        const float p = __expf((s_acc[n][r] - mnew) * 0.125f);
        s_acc[n][r] = p;
        rs += p;
      }
    rs += __shfl_xor(rs, 16, 64);
    rs += __shfl_xor(rs, 32, 64);
    l_i = l_i * alpha + rs;

#pragma unroll
    for (int n = 0; n < 4; ++n)
#pragma unroll
      for (int r = 0; r < 4; ++r) o_acc[n][r] *= alpha;

#pragma unroll
    for (int n = 0; n < 4; ++n) {
      union { bf16 hx[4]; uint2 u; } pk;
#pragma unroll
      for (int r = 0; r < 4; ++r) pk.hx[r] = __float2bfloat16(s_acc[n][r]);
      *(uint2*)&pl[col * 72 + n * 16 + fq * 4] = pk.u;
    }
    short8 pa[2];
#pragma unroll
    for (int ks = 0; ks < 2; ++ks)
      pa[ks] = *(const short8*)&pl[col * 72 + ks * 32 + fq * 8];

#pragma unroll
    for (int n = 0; n < 4; ++n)
#pragma unroll
      for (int ks = 0; ks < 2; ++ks)
        o_acc[n] = mfma_bf16(vf[n * 2 + ks], pa[ks], o_acc[n]);
  }

  const float inv = 1.0f / l_i;
#pragma unroll
  for (int n = 0; n < 4; ++n) {
#pragma unroll
    for (int r = 0; r < 4; ++r) o_acc[n][r] *= inv;
    union { bf16 hx[4]; uint2 u; } ok;
#pragma unroll
    for (int r = 0; r < 4; ++r) ok.hx[r] = __float2bfloat16(o_acc[n][r]);
    *(uint2*)&attn_out[(size_t)q_glob * DMODEL + h * HDIM + n * 16 + fq * 4] = ok.u;
  }
}

// ---------------- GEMM2: out = attn @ Wo^T, fused residual+gate ----------------
// 64x128 tile (grid 512 = 2 blocks/CU) to fix grid starvation at M=N=2048.
// 4 waves; all share the 64-row A tile, wave w owns B cols w*32..w*32+31.
__global__ __launch_bounds__(256) void gemm_out(const bf16* __restrict__ A,
                                                const bf16* __restrict__ W,
                                                const float* __restrict__ xres,
                                                const float* __restrict__ gate,
                                                float* __restrict__ out) {
  constexpr int K = DMODEL;
  __shared__ bf16 As[64 * 32];
  __shared__ bf16 Bs[128 * 32];
  const int tid = threadIdx.x;
  const int wave = tid >> 6, lane = tid & 63;
  const int m0 = blockIdx.y * 64, n0 = blockIdx.x * 128;
  const int sr = lane >> 2;
  const int swc = (((lane & 3) ^ ((lane >> 3) & 3)) * 8);
  const int fr = lane & 15, fq = lane >> 4;
  const int rdc = ((fq ^ ((fr >> 1) & 3)) * 8);

  const f32x4 zero = {0.f, 0.f, 0.f, 0.f};
  f32x4 acc[4][2];
  for (int i = 0; i < 4; ++i)
    for (int j = 0; j < 2; ++j) acc[i][j] = zero;

  for (int kt = 0; kt < K; kt += 32) {
    __syncthreads();
    async_copy16(A + (size_t)(m0 + wave * 16 + sr) * K + kt + swc,
                 &As[(wave * 16) * 32]);
#pragma unroll
    for (int j = 0; j < 2; ++j)
      async_copy16(W + (size_t)(n0 + wave * 32 + j * 16 + sr) * K + kt + swc,
                   &Bs[(wave * 32 + j * 16) * 32]);
    __syncthreads();
    short8 a[4], b[2];
    for (int i = 0; i < 4; ++i)
      a[i] = *(const short8*)&As[(i * 16 + fr) * 32 + rdc];
    for (int j = 0; j < 2; ++j)
      b[j] = *(const short8*)&Bs[(wave * 32 + j * 16 + fr) * 32 + rdc];
    for (int i = 0; i < 4; ++i)
      for (int j = 0; j < 2; ++j)
        acc[i][j] = mfma_bf16(a[i], b[j], acc[i][j]);
  }

  const int col = fr, rq = fq * 4;
  for (int j = 0; j < 2; ++j) {
    const int cc = n0 + wave * 32 + j * 16 + col;
    const float g = gate[cc];
    for (int i = 0; i < 4; ++i) {
      const int base_row = m0 + i * 16 + rq;
      for (int r = 0; r < 4; ++r) {
        const size_t idx = (size_t)(base_row + r) * DMODEL + cc;
        out[idx] = xres[idx] + g * acc[i][j][r];
      }
    }
  }
}

extern "C" void kernel_launch(void* const* d_in, const int* in_sizes, int n_in,
                              void* d_out, int out_size, void* d_ws, size_t ws_size,
                              hipStream_t stream) {
  const float* x    = (const float*)d_in[0];
  const float* Wqkv = (const float*)d_in[1];
  const float* Wo   = (const float*)d_in[2];
  const float* gate = (const float*)d_in[3];
  float* out = (float*)d_out;

  char* ws = (char*)d_ws;
  const size_t MB = 1024 * 1024;
  bf16* xb      = (bf16*)(ws);                 // 8 MB   (dead after gemm_qkv)
  bf16* wqkvb   = (bf16*)(ws + 8 * MB);        // 24 MB  (dead after gemm_qkv)
  bf16* wob     = (bf16*)(ws + 32 * MB);       // 8 MB
  bf16* q_ws    = (bf16*)(ws + 40 * MB);       // 8 MB  [h][s][dh]
  bf16* k_ws    = (bf16*)(ws + 48 * MB);       // 8 MB  [h][s][dh]
  bf16* v_ws    = (bf16*)(ws + 56 * MB);       // 8 MB  [h][dh][s] (pre-transposed)
  bf16* attn_ws = (bf16*)(ws);                 // aliases xb

  cvt3_kernel<<<dim3(20480), 256, 0, stream>>>(x, xb, Wqkv, wqkvb, Wo, wob);

  gemm_qkv<<<dim3(NQKV / 128, DMODEL / 128), 256, 0, stream>>>(xb, wqkvb, q_ws, k_ws, v_ws);
  attn_kernel<<<dim3(1024), 256, 0, stream>>>(q_ws, k_ws, v_ws, attn_ws);
  gemm_out<<<dim3(DMODEL / 128, DMODEL / 64), 256, 0, stream>>>(attn_ws, wob, x, gate, out);
}